// Round 1
// baseline (797.141 us; speedup 1.0000x reference)
//
#include <hip/hip_runtime.h>

#define NN 20000
#define EE 320000
#define ETOT 340000
#define FIN 128
#define NH 6
#define FF 384
#define NOUT 10
#define NG 64
#define NEG 0.2f

typedef short short8 __attribute__((ext_vector_type(8)));
typedef float f32x4 __attribute__((ext_vector_type(4)));

// ---------------- static device storage (avoids ws_size dependence) ----------
__device__ float g_bufA[(size_t)NN * FF];   // gemm output h
__device__ float g_bufB[(size_t)NN * FF];   // conv output / layer input
__device__ float g_bufC[(size_t)NN * FF];   // xs2 storage
__device__ unsigned short g_featHi[(size_t)NN * FF];
__device__ unsigned short g_featLo[(size_t)NN * FF];
__device__ unsigned short g_xHi[(size_t)NN * FIN];
__device__ unsigned short g_xLo[(size_t)NN * FIN];
__device__ unsigned short g_WtHi[4][FF * FF];  // transposed weights [col][k]
__device__ unsigned short g_WtLo[4][FF * FF];
__device__ float g_alS[NN * NH];
__device__ float g_alD[NN * NH];
__device__ int g_rowptr[NN + 1];
__device__ int g_cnt[NN];
__device__ int g_cur[NN];
__device__ int g_colsrc[ETOT];

// ---------------- helpers ----------------------------------------------------
__device__ __forceinline__ unsigned short f2bf(float f) {
  unsigned u = __float_as_uint(f);
  u += 0x7FFFu + ((u >> 16) & 1u);
  return (unsigned short)(u >> 16);
}
__device__ __forceinline__ float bf2f(unsigned short s) {
  return __uint_as_float(((unsigned)s) << 16);
}

__device__ __forceinline__ void gl_lds16(const void* g, void* l) {
  // CK-style casts: global flat addr == AS1 addr; low 32 bits of flat LDS addr == LDS offset.
  __builtin_amdgcn_global_load_lds(
      (const __attribute__((address_space(1))) unsigned int*)(unsigned long long)g,
      (__attribute__((address_space(3))) unsigned int*)(unsigned int)(unsigned long long)l,
      16, 0, 0);
}

__device__ __forceinline__ void mfma_acc(f32x4& c, short8 a, short8 b) {
  asm("v_mfma_f32_16x16x32_bf16 %0, %1, %2, %0" : "+v"(c) : "v"(a), "v"(b));
}

// ---------------- weight prep: fp32 [K,F] -> bf16 hi/lo transposed [F][K] ----
__global__ __launch_bounds__(256) void k_wprep(const float* __restrict__ W, int K, int widx) {
  int i = blockIdx.x * 256 + threadIdx.x;
  if (i >= K * FF) return;
  int k = i / FF, c = i % FF;
  float v = W[i];
  unsigned short h = f2bf(v);
  g_WtHi[widx][c * K + k] = h;
  g_WtLo[widx][c * K + k] = f2bf(v - bf2f(h));
}

// ---------------- CSR build --------------------------------------------------
__global__ __launch_bounds__(256) void k_zero() {
  int i = blockIdx.x * 256 + threadIdx.x;
  if (i < NN) g_cnt[i] = 0;
}

__global__ __launch_bounds__(256) void k_hist(const int* __restrict__ ei) {
  int i = blockIdx.x * 256 + threadIdx.x;
  if (i >= ETOT) return;
  int d = (i < EE) ? ei[EE + i] : (i - EE);
  atomicAdd(&g_cnt[d], 1);
}

__global__ __launch_bounds__(256) void k_scan() {
  __shared__ int sh[256];
  __shared__ int carry;
  int tid = threadIdx.x;
  if (tid == 0) carry = 0;
  __syncthreads();
  for (int base = 0; base < NN; base += 256) {
    int i = base + tid;
    int v = (i < NN) ? g_cnt[i] : 0;
    sh[tid] = v;
    __syncthreads();
    for (int off = 1; off < 256; off <<= 1) {
      int t = (tid >= off) ? sh[tid - off] : 0;
      __syncthreads();
      sh[tid] += t;
      __syncthreads();
    }
    int incl = sh[tid];
    int c = carry;
    if (i < NN) { g_rowptr[i] = c + incl - v; g_cur[i] = c + incl - v; }
    __syncthreads();
    if (tid == 255) carry = c + sh[255];
    __syncthreads();
  }
  if (tid == 0) g_rowptr[NN] = carry;
}

__global__ __launch_bounds__(256) void k_scatter(const int* __restrict__ ei) {
  int i = blockIdx.x * 256 + threadIdx.x;
  if (i >= ETOT) return;
  int s, d;
  if (i < EE) { s = ei[i]; d = ei[EE + i]; } else { s = d = i - EE; }
  int pos = atomicAdd(&g_cur[d], 1);
  g_colsrc[pos] = s;
}

// ---------------- fp32 -> bf16 hi/lo split -----------------------------------
__global__ __launch_bounds__(256) void k_split(int sel, const float* __restrict__ xin) {
  int total = sel ? NN * FF : NN * FIN;
  const float* src = sel ? g_bufB : xin;
  unsigned short* oh = sel ? g_featHi : g_xHi;
  unsigned short* ol = sel ? g_featLo : g_xLo;
  int n4 = total >> 2;
  const float4* s4 = (const float4*)src;
  ushort4* oh4 = (ushort4*)oh;
  ushort4* ol4 = (ushort4*)ol;
  for (int i = blockIdx.x * blockDim.x + threadIdx.x; i < n4; i += gridDim.x * blockDim.x) {
    float4 v = s4[i];
    ushort4 h, l;
    h.x = f2bf(v.x); l.x = f2bf(v.x - bf2f(h.x));
    h.y = f2bf(v.y); l.y = f2bf(v.y - bf2f(h.y));
    h.z = f2bf(v.z); l.z = f2bf(v.z - bf2f(h.z));
    h.w = f2bf(v.w); l.w = f2bf(v.w - bf2f(h.w));
    oh4[i] = h; ol4[i] = l;
  }
}

// ---------------- GEMM: bufA = A @ Wt^T (3-term bf16 split, fp32 acc) --------
__global__ __launch_bounds__(256) void k_gemm(int asel, int widx, int K) {
  __shared__ unsigned short lA[128 * 64];
  __shared__ unsigned short lB[128 * 64];
  const unsigned short* Ah = asel ? g_featHi : g_xHi;
  const unsigned short* Al = asel ? g_featLo : g_xLo;
  const unsigned short* Bh = g_WtHi[widx];
  const unsigned short* Bl = g_WtLo[widx];
  const int m0 = blockIdx.x * 128;
  const int n0 = blockIdx.y * 128;
  const int tid = threadIdx.x;
  const int wave = tid >> 6, lane = tid & 63;
  const int wm = wave >> 1, wn = wave & 1;
  const int srow = lane >> 3;        // row within 8-row chunk
  const int scol = (lane & 7) * 8;   // k-element offset

  f32x4 acc[4][4] = {};

  for (int t = 0; t < 3; ++t) {
    const unsigned short* Ap = (t == 1) ? Al : Ah;
    const unsigned short* Bp = (t == 2) ? Bl : Bh;
    for (int k0 = 0; k0 < K; k0 += 64) {
      __syncthreads();  // prior reads done before overwrite
      #pragma unroll
      for (int it = 0; it < 4; ++it) {
        int c = wave * 4 + it;
        int rA = c * 8 + srow;
        int gr = m0 + rA; gr = (gr < NN) ? gr : (NN - 1);
        gl_lds16(Ap + (size_t)gr * K + k0 + scol, (unsigned short*)lA + c * 512);
        int cB = n0 + rA;  // always < 384
        gl_lds16(Bp + (size_t)cB * K + k0 + scol, (unsigned short*)lB + c * 512);
      }
      __syncthreads();  // drains vmcnt for global_load_lds
      #pragma unroll
      for (int kk = 0; kk < 64; kk += 32) {
        const int kb = kk + (lane >> 4) * 8;
        const int r16 = lane & 15;
        short8 af[4], bfr[4];
        #pragma unroll
        for (int mf = 0; mf < 4; ++mf)
          af[mf] = *(const short8*)&lA[(wm * 64 + mf * 16 + r16) * 64 + kb];
        #pragma unroll
        for (int nf = 0; nf < 4; ++nf)
          bfr[nf] = *(const short8*)&lB[(wn * 64 + nf * 16 + r16) * 64 + kb];
        #pragma unroll
        for (int mf = 0; mf < 4; ++mf)
          #pragma unroll
          for (int nf = 0; nf < 4; ++nf)
            mfma_acc(acc[mf][nf], af[mf], bfr[nf]);
      }
    }
  }
  asm volatile("s_nop 7\n\ts_nop 7" :::);
  #pragma unroll
  for (int mf = 0; mf < 4; ++mf) {
    #pragma unroll
    for (int nf = 0; nf < 4; ++nf) {
      int col = n0 + wn * 64 + nf * 16 + (lane & 15);
      int rb = m0 + wm * 64 + mf * 16 + ((lane >> 4) << 2);
      #pragma unroll
      for (int j = 0; j < 4; ++j) {
        int r = rb + j;
        if (r < NN) g_bufA[(size_t)r * FF + col] = acc[mf][nf][j];
      }
    }
  }
}

// ---------------- per-node attention coefficients ----------------------------
__global__ __launch_bounds__(256) void k_alpha(const float* __restrict__ asr,
                                               const float* __restrict__ adt) {
  int node = blockIdx.x * 4 + (threadIdx.x >> 6);
  int lane = threadIdx.x & 63;
  if (node >= NN) return;
  const float* hrow = g_bufA + (size_t)node * FF;
  #pragma unroll
  for (int h = 0; h < NH; ++h) {
    float v = hrow[h * 64 + lane];
    float ps = v * asr[h * 64 + lane];
    float pd = v * adt[h * 64 + lane];
    #pragma unroll
    for (int off = 32; off > 0; off >>= 1) {
      ps += __shfl_down(ps, off);
      pd += __shfl_down(pd, off);
    }
    if (lane == 0) { g_alS[node * NH + h] = ps; g_alD[node * NH + h] = pd; }
  }
}

// ---------------- softmax + aggregation, one wave per destination node -------
__global__ __launch_bounds__(256) void k_edge(const float* __restrict__ bias, int outsel) {
  float* out = outsel ? g_bufC : g_bufB;
  int node = blockIdx.x * 4 + (threadIdx.x >> 6);
  int lane = threadIdx.x & 63;
  if (node >= NN) return;
  const int lo = g_rowptr[node], hi = g_rowptr[node + 1];
  float ad[NH];
  #pragma unroll
  for (int h = 0; h < NH; ++h) ad[h] = g_alD[node * NH + h];
  float m[NH];
  #pragma unroll
  for (int h = 0; h < NH; ++h) m[h] = -1e30f;
  // pass 1: wave-parallel max per head
  for (int e = lo + lane; e < hi; e += 64) {
    int s = g_colsrc[e];
    #pragma unroll
    for (int h = 0; h < NH; ++h) {
      float v = g_alS[s * NH + h] + ad[h];
      v = (v > 0.f) ? v : NEG * v;
      m[h] = fmaxf(m[h], v);
    }
  }
  #pragma unroll
  for (int h = 0; h < NH; ++h)
    #pragma unroll
    for (int off = 32; off > 0; off >>= 1)
      m[h] = fmaxf(m[h], __shfl_xor(m[h], off));
  // pass 2: un-normalized weighted aggregation + denominator
  float acc[NH] = {0.f, 0.f, 0.f, 0.f, 0.f, 0.f};
  float ssum[NH] = {0.f, 0.f, 0.f, 0.f, 0.f, 0.f};
  for (int e = lo; e < hi; ++e) {
    int s = g_colsrc[e];
    const float* hrow = g_bufA + (size_t)s * FF;
    #pragma unroll
    for (int h = 0; h < NH; ++h) {
      float v = g_alS[s * NH + h] + ad[h];
      v = (v > 0.f) ? v : NEG * v;
      float w = __expf(v - m[h]);
      ssum[h] += w;
      acc[h] = fmaf(w, hrow[h * 64 + lane], acc[h]);
    }
  }
  #pragma unroll
  for (int h = 0; h < NH; ++h) {
    float o = acc[h] / (ssum[h] + 1e-16f) + bias[h * 64 + lane];
    out[(size_t)node * FF + h * 64 + lane] = fmaxf(o, 0.f);
  }
}

// ---------------- global mean pool (batch is sorted) -------------------------
__global__ __launch_bounds__(384) void k_pool(const int* __restrict__ batch,
                                              float* __restrict__ dout) {
  int g = blockIdx.x;
  int d = threadIdx.x;
  int lo = 0, hi = NN;
  while (lo < hi) { int mid = (lo + hi) >> 1; if (batch[mid] < g) lo = mid + 1; else hi = mid; }
  int s0 = lo;
  lo = 0; hi = NN;
  while (lo < hi) { int mid = (lo + hi) >> 1; if (batch[mid] < g + 1) lo = mid + 1; else hi = mid; }
  int s1 = lo;
  float acc = 0.f;
  for (int n = s0; n < s1; ++n)
    acc += g_bufB[(size_t)n * FF + d] + g_bufC[(size_t)n * FF + d];
  int cnt = s1 - s0;
  float denom = (cnt > 0) ? (float)cnt : 1.f;
  dout[NG * NOUT + g * FF + d] = acc / denom;
}

// ---------------- readout MLP ------------------------------------------------
__global__ __launch_bounds__(64) void k_mlp(const float* __restrict__ r1w,
                                            const float* __restrict__ r1b,
                                            const float* __restrict__ r2w,
                                            const float* __restrict__ r2b,
                                            float* __restrict__ dout) {
  int g = blockIdx.x;
  int t = threadIdx.x;
  __shared__ float hid[64];
  const float* xr = dout + NG * NOUT + g * FF;
  float acc = r1b[t];
  for (int k = 0; k < FF; ++k) acc = fmaf(xr[k], r1w[k * 64 + t], acc);
  hid[t] = fmaxf(acc, 0.f);
  __syncthreads();
  if (t < NOUT) {
    float o = r2b[t];
    #pragma unroll
    for (int j = 0; j < 64; ++j) o = fmaf(hid[j], r2w[j * NOUT + t], o);
    dout[g * NOUT + t] = o;
  }
}

// ---------------- orchestration ----------------------------------------------
extern "C" void kernel_launch(void* const* d_in, const int* in_sizes, int n_in,
                              void* d_out, int out_size, void* d_ws, size_t ws_size,
                              hipStream_t stream) {
  const float* x    = (const float*)d_in[0];
  const int* ei     = (const int*)d_in[1];
  const int* batch  = (const int*)d_in[2];
  const float* W1   = (const float*)d_in[3];
  const float* a1s  = (const float*)d_in[4];
  const float* a1d  = (const float*)d_in[5];
  const float* b1   = (const float*)d_in[6];
  const float* W2   = (const float*)d_in[7];
  const float* a2s  = (const float*)d_in[8];
  const float* a2d  = (const float*)d_in[9];
  const float* b2   = (const float*)d_in[10];
  const float* Ws1  = (const float*)d_in[11];
  const float* as1s = (const float*)d_in[12];
  const float* as1d = (const float*)d_in[13];
  const float* bs1  = (const float*)d_in[14];
  const float* Ws2  = (const float*)d_in[15];
  const float* as2s = (const float*)d_in[16];
  const float* as2d = (const float*)d_in[17];
  const float* bs2  = (const float*)d_in[18];
  const float* r1w  = (const float*)d_in[19];
  const float* r1b  = (const float*)d_in[20];
  const float* r2w  = (const float*)d_in[21];
  const float* r2b  = (const float*)d_in[22];
  float* out = (float*)d_out;

  dim3 b256(256);
  // weight prep (widx: 0=Ws1, 1=Ws2, 2=W1, 3=W2)
  k_wprep<<<dim3((FIN * FF + 255) / 256), b256, 0, stream>>>(Ws1, FIN, 0);
  k_wprep<<<dim3((FF * FF + 255) / 256), b256, 0, stream>>>(Ws2, FF, 1);
  k_wprep<<<dim3((FIN * FF + 255) / 256), b256, 0, stream>>>(W1, FIN, 2);
  k_wprep<<<dim3((FF * FF + 255) / 256), b256, 0, stream>>>(W2, FF, 3);
  // CSR by destination
  k_zero<<<dim3((NN + 255) / 256), b256, 0, stream>>>();
  k_hist<<<dim3((ETOT + 255) / 256), b256, 0, stream>>>(ei);
  k_scan<<<dim3(1), b256, 0, stream>>>();
  k_scatter<<<dim3((ETOT + 255) / 256), b256, 0, stream>>>(ei);
  // split x once (reused by both branch-1 convs)
  k_split<<<dim3(2048), b256, 0, stream>>>(0, x);

  dim3 gemmGrid((NN + 127) / 128, FF / 128);
  dim3 nodeGrid((NN + 3) / 4);

  // skip branch, layer 1: bufB = relu(conv(x, Ws1))
  k_gemm<<<gemmGrid, b256, 0, stream>>>(0, 0, FIN);
  k_alpha<<<nodeGrid, b256, 0, stream>>>(as1s, as1d);
  k_edge<<<nodeGrid, b256, 0, stream>>>(bs1, 0);
  // skip branch, layer 2: bufC = relu(conv(bufB, Ws2))
  k_split<<<dim3(2048), b256, 0, stream>>>(1, nullptr);
  k_gemm<<<gemmGrid, b256, 0, stream>>>(1, 1, FF);
  k_alpha<<<nodeGrid, b256, 0, stream>>>(as2s, as2d);
  k_edge<<<nodeGrid, b256, 0, stream>>>(bs2, 1);
  // main branch, layer 1: bufB = relu(conv(x, W1))
  k_gemm<<<gemmGrid, b256, 0, stream>>>(0, 2, FIN);
  k_alpha<<<nodeGrid, b256, 0, stream>>>(a1s, a1d);
  k_edge<<<nodeGrid, b256, 0, stream>>>(b1, 0);
  // main branch, layer 2: bufB = relu(conv(bufB, W2))
  k_split<<<dim3(2048), b256, 0, stream>>>(1, nullptr);
  k_gemm<<<gemmGrid, b256, 0, stream>>>(1, 3, FF);
  k_alpha<<<nodeGrid, b256, 0, stream>>>(a2s, a2d);
  k_edge<<<nodeGrid, b256, 0, stream>>>(b2, 0);
  // pool (bufB + bufC) and MLP
  k_pool<<<dim3(NG), dim3(FF), 0, stream>>>(batch, out);
  k_mlp<<<dim3(NG), dim3(64), 0, stream>>>(r1w, r1b, r2w, r2b, out);
}

// Round 3
// 706.073 us; speedup vs baseline: 1.1290x; 1.1290x over previous
//
#include <hip/hip_runtime.h>

#define NN 20000
#define EE 320000
#define ETOT 340000
#define FIN 128
#define NH 6
#define FF 384
#define NOUT 10
#define NG 64
#define NEG 0.2f
#define PCH 32

typedef short short8 __attribute__((ext_vector_type(8)));
typedef float f32x4 __attribute__((ext_vector_type(4)));

// ---------------- static device storage (avoids ws_size dependence) ----------
__device__ float g_bufA[(size_t)NN * FF];   // gemm output h
__device__ float g_bufB[(size_t)NN * FF];   // conv output / layer input
__device__ float g_bufC[(size_t)NN * FF];   // xs2 storage
__device__ unsigned short g_featHi[(size_t)NN * FF];
__device__ unsigned short g_featLo[(size_t)NN * FF];
__device__ unsigned short g_xHi[(size_t)NN * FIN];
__device__ unsigned short g_xLo[(size_t)NN * FIN];
__device__ unsigned short g_WtHi[4][FF * FF];  // transposed weights [col][k]
__device__ unsigned short g_WtLo[4][FF * FF];
__device__ float g_alS[NN * NH];
__device__ float g_alD[NN * NH];
__device__ int g_rowptr[NN + 1];
__device__ int g_cnt[NN];
__device__ int g_cur[NN];
__device__ int g_colsrc[ETOT];
__device__ float g_pool[NG * FF];
__device__ int g_gcnt[NG];

// ---------------- helpers ----------------------------------------------------
__device__ __forceinline__ unsigned short f2bf(float f) {
  unsigned u = __float_as_uint(f);
  u += 0x7FFFu + ((u >> 16) & 1u);
  return (unsigned short)(u >> 16);
}
__device__ __forceinline__ float bf2f(unsigned short s) {
  return __uint_as_float(((unsigned)s) << 16);
}

__device__ __forceinline__ void gl_lds16(const void* g, void* l) {
  __builtin_amdgcn_global_load_lds(
      (const __attribute__((address_space(1))) unsigned int*)(unsigned long long)g,
      (__attribute__((address_space(3))) unsigned int*)(unsigned int)(unsigned long long)l,
      16, 0, 0);
}

__device__ __forceinline__ void mfma_acc(f32x4& c, short8 a, short8 b) {
  asm("v_mfma_f32_16x16x32_bf16 %0, %1, %2, %0" : "+v"(c) : "v"(a), "v"(b));
}

// ---------------- weight prep: fp32 [K,F] -> bf16 hi/lo transposed [F][K] ----
__global__ __launch_bounds__(256) void k_wprep(const float* __restrict__ W, int K, int widx) {
  int i = blockIdx.x * 256 + threadIdx.x;
  if (i >= K * FF) return;
  int k = i / FF, c = i % FF;
  float v = W[i];
  unsigned short h = f2bf(v);
  g_WtHi[widx][c * K + k] = h;
  g_WtLo[widx][c * K + k] = f2bf(v - bf2f(h));
}

// ---------------- zero pass (CSR histogram + pool accumulators) --------------
__global__ __launch_bounds__(256) void k_zero() {
  int i = blockIdx.x * 256 + threadIdx.x;
  if (i < NN) g_cnt[i] = 0;
  if (i < NG * FF) g_pool[i] = 0.f;
  if (i < NG) g_gcnt[i] = 0;
}

__global__ __launch_bounds__(256) void k_hist(const int* __restrict__ ei) {
  int i = blockIdx.x * 256 + threadIdx.x;
  if (i >= ETOT) return;
  int d = (i < EE) ? ei[EE + i] : (i - EE);
  atomicAdd(&g_cnt[d], 1);
}

__global__ __launch_bounds__(256) void k_scan() {
  __shared__ int sh[256];
  __shared__ int carry;
  int tid = threadIdx.x;
  if (tid == 0) carry = 0;
  __syncthreads();
  for (int base = 0; base < NN; base += 256) {
    int i = base + tid;
    int v = (i < NN) ? g_cnt[i] : 0;
    sh[tid] = v;
    __syncthreads();
    for (int off = 1; off < 256; off <<= 1) {
      int t = (tid >= off) ? sh[tid - off] : 0;
      __syncthreads();
      sh[tid] += t;
      __syncthreads();
    }
    int incl = sh[tid];
    int c = carry;
    if (i < NN) { g_rowptr[i] = c + incl - v; g_cur[i] = c + incl - v; }
    __syncthreads();
    if (tid == 255) carry = c + sh[255];
    __syncthreads();
  }
  if (tid == 0) g_rowptr[NN] = carry;
}

__global__ __launch_bounds__(256) void k_scatter(const int* __restrict__ ei) {
  int i = blockIdx.x * 256 + threadIdx.x;
  if (i >= ETOT) return;
  int s, d;
  if (i < EE) { s = ei[i]; d = ei[EE + i]; } else { s = d = i - EE; }
  int pos = atomicAdd(&g_cur[d], 1);
  g_colsrc[pos] = s;
}

// ---------------- fp32 -> bf16 hi/lo split -----------------------------------
__global__ __launch_bounds__(256) void k_split(int sel, const float* __restrict__ xin) {
  int total = sel ? NN * FF : NN * FIN;
  const float* src = sel ? g_bufB : xin;
  unsigned short* oh = sel ? g_featHi : g_xHi;
  unsigned short* ol = sel ? g_featLo : g_xLo;
  int n4 = total >> 2;
  const float4* s4 = (const float4*)src;
  ushort4* oh4 = (ushort4*)oh;
  ushort4* ol4 = (ushort4*)ol;
  for (int i = blockIdx.x * blockDim.x + threadIdx.x; i < n4; i += gridDim.x * blockDim.x) {
    float4 v = s4[i];
    ushort4 h, l;
    h.x = f2bf(v.x); l.x = f2bf(v.x - bf2f(h.x));
    h.y = f2bf(v.y); l.y = f2bf(v.y - bf2f(h.y));
    h.z = f2bf(v.z); l.z = f2bf(v.z - bf2f(h.z));
    h.w = f2bf(v.w); l.w = f2bf(v.w - bf2f(h.w));
    oh4[i] = h; ol4[i] = l;
  }
}

// ---------------- GEMM: bufA = A @ Wt^T (3-term bf16 split, fp32 acc) --------
__global__ __launch_bounds__(256) void k_gemm(int asel, int widx, int K) {
  __shared__ unsigned short lA[128 * 64];
  __shared__ unsigned short lB[128 * 64];
  const unsigned short* Ah = asel ? g_featHi : g_xHi;
  const unsigned short* Al = asel ? g_featLo : g_xLo;
  const unsigned short* Bh = g_WtHi[widx];
  const unsigned short* Bl = g_WtLo[widx];
  const int m0 = blockIdx.x * 128;
  const int n0 = blockIdx.y * 128;
  const int tid = threadIdx.x;
  const int wave = tid >> 6, lane = tid & 63;
  const int wm = wave >> 1, wn = wave & 1;
  const int srow = lane >> 3;        // row within 8-row chunk
  const int scol = (lane & 7) * 8;   // k-element offset

  f32x4 acc[4][4] = {};

  for (int t = 0; t < 3; ++t) {
    const unsigned short* Ap = (t == 1) ? Al : Ah;
    const unsigned short* Bp = (t == 2) ? Bl : Bh;
    for (int k0 = 0; k0 < K; k0 += 64) {
      __syncthreads();  // prior reads done before overwrite
      #pragma unroll
      for (int it = 0; it < 4; ++it) {
        int c = wave * 4 + it;
        int rA = c * 8 + srow;
        int gr = m0 + rA; gr = (gr < NN) ? gr : (NN - 1);
        gl_lds16(Ap + (size_t)gr * K + k0 + scol, (unsigned short*)lA + c * 512);
        int cB = n0 + rA;  // always < 384
        gl_lds16(Bp + (size_t)cB * K + k0 + scol, (unsigned short*)lB + c * 512);
      }
      __syncthreads();  // drains vmcnt for global_load_lds
      #pragma unroll
      for (int kk = 0; kk < 64; kk += 32) {
        const int kb = kk + (lane >> 4) * 8;
        const int r16 = lane & 15;
        short8 af[4], bfr[4];
        #pragma unroll
        for (int mf = 0; mf < 4; ++mf)
          af[mf] = *(const short8*)&lA[(wm * 64 + mf * 16 + r16) * 64 + kb];
        #pragma unroll
        for (int nf = 0; nf < 4; ++nf)
          bfr[nf] = *(const short8*)&lB[(wn * 64 + nf * 16 + r16) * 64 + kb];
        #pragma unroll
        for (int mf = 0; mf < 4; ++mf)
          #pragma unroll
          for (int nf = 0; nf < 4; ++nf)
            mfma_acc(acc[mf][nf], af[mf], bfr[nf]);
      }
    }
  }
  asm volatile("s_nop 7\n\ts_nop 7" :::);
  #pragma unroll
  for (int mf = 0; mf < 4; ++mf) {
    #pragma unroll
    for (int nf = 0; nf < 4; ++nf) {
      int col = n0 + wn * 64 + nf * 16 + (lane & 15);
      int rb = m0 + wm * 64 + mf * 16 + ((lane >> 4) << 2);
      #pragma unroll
      for (int j = 0; j < 4; ++j) {
        int r = rb + j;
        if (r < NN) g_bufA[(size_t)r * FF + col] = acc[mf][nf][j];
      }
    }
  }
}

// ---------------- per-node attention coefficients ----------------------------
__global__ __launch_bounds__(256) void k_alpha(const float* __restrict__ asr,
                                               const float* __restrict__ adt) {
  int node = blockIdx.x * 4 + (threadIdx.x >> 6);
  int lane = threadIdx.x & 63;
  if (node >= NN) return;
  const float* hrow = g_bufA + (size_t)node * FF;
  #pragma unroll
  for (int h = 0; h < NH; ++h) {
    float v = hrow[h * 64 + lane];
    float ps = v * asr[h * 64 + lane];
    float pd = v * adt[h * 64 + lane];
    #pragma unroll
    for (int off = 32; off > 0; off >>= 1) {
      ps += __shfl_down(ps, off);
      pd += __shfl_down(pd, off);
    }
    if (lane == 0) { g_alS[node * NH + h] = ps; g_alD[node * NH + h] = pd; }
  }
}

// ---------------- softmax + aggregation, one wave per destination node -------
__global__ __launch_bounds__(256) void k_edge(const float* __restrict__ bias, int outsel) {
  float* out = outsel ? g_bufC : g_bufB;
  int node = blockIdx.x * 4 + (threadIdx.x >> 6);
  int lane = threadIdx.x & 63;
  if (node >= NN) return;
  const int lo = g_rowptr[node], hi = g_rowptr[node + 1];
  float ad[NH];
  #pragma unroll
  for (int h = 0; h < NH; ++h) ad[h] = g_alD[node * NH + h];
  float m[NH];
  #pragma unroll
  for (int h = 0; h < NH; ++h) m[h] = -1e30f;
  // pass 1: wave-parallel max per head
  for (int e = lo + lane; e < hi; e += 64) {
    int s = g_colsrc[e];
    #pragma unroll
    for (int h = 0; h < NH; ++h) {
      float v = g_alS[s * NH + h] + ad[h];
      v = (v > 0.f) ? v : NEG * v;
      m[h] = fmaxf(m[h], v);
    }
  }
  #pragma unroll
  for (int h = 0; h < NH; ++h)
    #pragma unroll
    for (int off = 32; off > 0; off >>= 1)
      m[h] = fmaxf(m[h], __shfl_xor(m[h], off));
  // pass 2: un-normalized weighted aggregation + denominator
  float acc[NH] = {0.f, 0.f, 0.f, 0.f, 0.f, 0.f};
  float ssum[NH] = {0.f, 0.f, 0.f, 0.f, 0.f, 0.f};
  for (int e = lo; e < hi; ++e) {
    int s = g_colsrc[e];
    const float* hrow = g_bufA + (size_t)s * FF;
    #pragma unroll
    for (int h = 0; h < NH; ++h) {
      float v = g_alS[s * NH + h] + ad[h];
      v = (v > 0.f) ? v : NEG * v;
      float w = __expf(v - m[h]);
      ssum[h] += w;
      acc[h] = fmaf(w, hrow[h * 64 + lane], acc[h]);
    }
  }
  #pragma unroll
  for (int h = 0; h < NH; ++h) {
    float o = acc[h] / (ssum[h] + 1e-16f) + bias[h * 64 + lane];
    out[(size_t)node * FF + h * 64 + lane] = fmaxf(o, 0.f);
  }
}

// ---------------- pooling: segmented accumulation over sorted batch ----------
__global__ __launch_bounds__(384) void k_pool_acc(const int* __restrict__ batch) {
  int n0 = blockIdx.x * PCH;
  if (n0 >= NN) return;
  int n1 = n0 + PCH; if (n1 > NN) n1 = NN;
  int d = threadIdx.x;
  int cur = batch[n0];
  float acc = 0.f;
  int cnt = 0;
  for (int n = n0; n < n1; ++n) {
    int g = batch[n];
    if (g != cur) {
      atomicAdd(&g_pool[cur * FF + d], acc);
      if (d == 0) atomicAdd(&g_gcnt[cur], cnt);
      acc = 0.f; cnt = 0; cur = g;
    }
    acc += g_bufB[(size_t)n * FF + d] + g_bufC[(size_t)n * FF + d];
    ++cnt;
  }
  atomicAdd(&g_pool[cur * FF + d], acc);
  if (d == 0) atomicAdd(&g_gcnt[cur], cnt);
}

// ---------------- finish: mean + readout MLP (fused) -------------------------
__global__ __launch_bounds__(384) void k_finish(const float* __restrict__ r1w,
                                                const float* __restrict__ r1b,
                                                const float* __restrict__ r2w,
                                                const float* __restrict__ r2b,
                                                float* __restrict__ dout) {
  int g = blockIdx.x;
  int d = threadIdx.x;
  __shared__ float xr[FF];
  __shared__ float hid[64];
  int cnt = g_gcnt[g];
  float denom = (cnt > 0) ? (float)cnt : 1.f;
  float v = g_pool[g * FF + d] / denom;
  xr[d] = v;
  dout[NG * NOUT + g * FF + d] = v;
  __syncthreads();
  if (d < 64) {
    float acc = r1b[d];
    for (int k = 0; k < FF; ++k) acc = fmaf(xr[k], r1w[k * 64 + d], acc);
    hid[d] = fmaxf(acc, 0.f);
  }
  __syncthreads();
  if (d < NOUT) {
    float o = r2b[d];
    #pragma unroll
    for (int j = 0; j < 64; ++j) o = fmaf(hid[j], r2w[j * NOUT + d], o);
    dout[g * NOUT + d] = o;
  }
}

// ---------------- orchestration ----------------------------------------------
extern "C" void kernel_launch(void* const* d_in, const int* in_sizes, int n_in,
                              void* d_out, int out_size, void* d_ws, size_t ws_size,
                              hipStream_t stream) {
  const float* x    = (const float*)d_in[0];
  const int* ei     = (const int*)d_in[1];
  const int* batch  = (const int*)d_in[2];
  const float* W1   = (const float*)d_in[3];
  const float* a1s  = (const float*)d_in[4];
  const float* a1d  = (const float*)d_in[5];
  const float* b1   = (const float*)d_in[6];
  const float* W2   = (const float*)d_in[7];
  const float* a2s  = (const float*)d_in[8];
  const float* a2d  = (const float*)d_in[9];
  const float* b2   = (const float*)d_in[10];
  const float* Ws1  = (const float*)d_in[11];
  const float* as1s = (const float*)d_in[12];
  const float* as1d = (const float*)d_in[13];
  const float* bs1  = (const float*)d_in[14];
  const float* Ws2  = (const float*)d_in[15];
  const float* as2s = (const float*)d_in[16];
  const float* as2d = (const float*)d_in[17];
  const float* bs2  = (const float*)d_in[18];
  const float* r1w  = (const float*)d_in[19];
  const float* r1b  = (const float*)d_in[20];
  const float* r2w  = (const float*)d_in[21];
  const float* r2b  = (const float*)d_in[22];
  float* out = (float*)d_out;

  dim3 b256(256);
  // weight prep (widx: 0=Ws1, 1=Ws2, 2=W1, 3=W2)
  k_wprep<<<dim3((FIN * FF + 255) / 256), b256, 0, stream>>>(Ws1, FIN, 0);
  k_wprep<<<dim3((FF * FF + 255) / 256), b256, 0, stream>>>(Ws2, FF, 1);
  k_wprep<<<dim3((FIN * FF + 255) / 256), b256, 0, stream>>>(W1, FIN, 2);
  k_wprep<<<dim3((FF * FF + 255) / 256), b256, 0, stream>>>(W2, FF, 3);
  // zero (CSR histogram + pool accumulators)
  k_zero<<<dim3((NG * FF + 255) / 256), b256, 0, stream>>>();
  k_hist<<<dim3((ETOT + 255) / 256), b256, 0, stream>>>(ei);
  k_scan<<<dim3(1), b256, 0, stream>>>();
  k_scatter<<<dim3((ETOT + 255) / 256), b256, 0, stream>>>(ei);
  // split x once (reused by both branch-1 convs)
  k_split<<<dim3(2048), b256, 0, stream>>>(0, x);

  dim3 gemmGrid((NN + 127) / 128, FF / 128);
  dim3 nodeGrid((NN + 3) / 4);

  // skip branch, layer 1: bufB = relu(conv(x, Ws1))
  k_gemm<<<gemmGrid, b256, 0, stream>>>(0, 0, FIN);
  k_alpha<<<nodeGrid, b256, 0, stream>>>(as1s, as1d);
  k_edge<<<nodeGrid, b256, 0, stream>>>(bs1, 0);
  // skip branch, layer 2: bufC = relu(conv(bufB, Ws2))
  k_split<<<dim3(2048), b256, 0, stream>>>(1, nullptr);
  k_gemm<<<gemmGrid, b256, 0, stream>>>(1, 1, FF);
  k_alpha<<<nodeGrid, b256, 0, stream>>>(as2s, as2d);
  k_edge<<<nodeGrid, b256, 0, stream>>>(bs2, 1);
  // main branch, layer 1: bufB = relu(conv(x, W1))
  k_gemm<<<gemmGrid, b256, 0, stream>>>(0, 2, FIN);
  k_alpha<<<nodeGrid, b256, 0, stream>>>(a1s, a1d);
  k_edge<<<nodeGrid, b256, 0, stream>>>(b1, 0);
  // main branch, layer 2: bufB = relu(conv(bufB, W2))
  k_split<<<dim3(2048), b256, 0, stream>>>(1, nullptr);
  k_gemm<<<gemmGrid, b256, 0, stream>>>(1, 3, FF);
  k_alpha<<<nodeGrid, b256, 0, stream>>>(a2s, a2d);
  k_edge<<<nodeGrid, b256, 0, stream>>>(b2, 0);
  // pool (bufB + bufC) and readout
  k_pool_acc<<<dim3((NN + PCH - 1) / PCH), dim3(384), 0, stream>>>(batch);
  k_finish<<<dim3(NG), dim3(384), 0, stream>>>(r1w, r1b, r2w, r2b, out);
}

// Round 5
// 625.400 us; speedup vs baseline: 1.2746x; 1.1290x over previous
//
#include <hip/hip_runtime.h>

#define NN 20000
#define EE 320000
#define ETOT 340000
#define FIN 128
#define NH 6
#define FF 384
#define NOUT 10
#define NG 64
#define NEG 0.2f
#define PCH 32
#define NB ((NN + 255) / 256)

typedef short short8 __attribute__((ext_vector_type(8)));
typedef float f32x4 __attribute__((ext_vector_type(4)));

// ---------------- static device storage (avoids ws_size dependence) ----------
__device__ float g_bufA[(size_t)NN * FF];   // gemm output h
__device__ float g_bufB[(size_t)NN * FF];   // conv output / layer input
__device__ float g_bufC[(size_t)NN * FF];   // xs2 storage
__device__ unsigned short g_featHi[(size_t)NN * FF];
__device__ unsigned short g_featLo[(size_t)NN * FF];
__device__ unsigned short g_xHi[(size_t)NN * FIN];
__device__ unsigned short g_xLo[(size_t)NN * FIN];
__device__ unsigned short g_WtHi[4][FF * FF];  // transposed weights [col][k]
__device__ unsigned short g_WtLo[4][FF * FF];
__device__ float g_alS[NN * NH];
__device__ float g_alD[NN * NH];
__device__ int g_rowptr[NN + 1];
__device__ int g_cnt[NN];
__device__ int g_cur[NN];
__device__ int g_blocksum[NB];
__device__ int g_colsrc[ETOT];
__device__ float g_pool[NG * FF];
__device__ int g_gcnt[NG];

// ---------------- helpers ----------------------------------------------------
__device__ __forceinline__ unsigned short f2bf(float f) {
  unsigned u = __float_as_uint(f);
  u += 0x7FFFu + ((u >> 16) & 1u);
  return (unsigned short)(u >> 16);
}
__device__ __forceinline__ float bf2f(unsigned short s) {
  return __uint_as_float(((unsigned)s) << 16);
}

__device__ __forceinline__ void gl_lds16(const void* g, void* l) {
  __builtin_amdgcn_global_load_lds(
      (const __attribute__((address_space(1))) unsigned int*)(unsigned long long)g,
      (__attribute__((address_space(3))) unsigned int*)(unsigned int)(unsigned long long)l,
      16, 0, 0);
}

__device__ __forceinline__ void mfma_acc(f32x4& c, short8 a, short8 b) {
  asm("v_mfma_f32_16x16x32_bf16 %0, %1, %2, %0" : "+v"(c) : "v"(a), "v"(b));
}

// ---------------- weight prep: fp32 [K,F] -> bf16 hi/lo transposed [F][K] ----
__global__ __launch_bounds__(256) void k_wprep(const float* __restrict__ W, int K, int widx) {
  int i = blockIdx.x * 256 + threadIdx.x;
  if (i >= K * FF) return;
  int k = i / FF, c = i % FF;
  float v = W[i];
  unsigned short h = f2bf(v);
  g_WtHi[widx][c * K + k] = h;
  g_WtLo[widx][c * K + k] = f2bf(v - bf2f(h));
}

// ---------------- zero pass (CSR histogram + pool accumulators) --------------
__global__ __launch_bounds__(256) void k_zero() {
  int i = blockIdx.x * 256 + threadIdx.x;
  if (i < NN) g_cnt[i] = 0;
  if (i < NG * FF) g_pool[i] = 0.f;
  if (i < NG) g_gcnt[i] = 0;
}

__global__ __launch_bounds__(256) void k_hist(const int* __restrict__ ei) {
  int i = blockIdx.x * 256 + threadIdx.x;
  if (i >= ETOT) return;
  int d = (i < EE) ? ei[EE + i] : (i - EE);
  atomicAdd(&g_cnt[d], 1);
}

// ---------------- hierarchical scan (3 launches, shuffle-based) --------------
__global__ __launch_bounds__(256) void k_scan_blk() {
  int b = blockIdx.x;
  int tid = threadIdx.x;
  int i = b * 256 + tid;
  int lane = tid & 63, wid = tid >> 6;
  int v = (i < NN) ? g_cnt[i] : 0;
  int s = v;
  #pragma unroll
  for (int off = 1; off < 64; off <<= 1) {
    int t = __shfl_up(s, off);
    if (lane >= off) s += t;
  }
  __shared__ int wsum[4];
  if (lane == 63) wsum[wid] = s;
  __syncthreads();
  int woff = 0;
  #pragma unroll
  for (int w = 0; w < 4; ++w) woff += (w < wid) ? wsum[w] : 0;
  if (i < NN) g_rowptr[i] = woff + s - v;   // block-local exclusive
  if (tid == 0) g_blocksum[b] = wsum[0] + wsum[1] + wsum[2] + wsum[3];
}

__global__ __launch_bounds__(128) void k_scan_top() {
  int tid = threadIdx.x;
  int lane = tid & 63, wid = tid >> 6;
  int v = (tid < NB) ? g_blocksum[tid] : 0;
  int s = v;
  #pragma unroll
  for (int off = 1; off < 64; off <<= 1) {
    int t = __shfl_up(s, off);
    if (lane >= off) s += t;
  }
  __shared__ int wsum[2];
  if (lane == 63) wsum[wid] = s;
  __syncthreads();
  int woff = (wid == 1) ? wsum[0] : 0;
  int excl = woff + s - v;
  if (tid < NB) g_blocksum[tid] = excl;
  if (tid == NB - 1) g_rowptr[NN] = excl + v;
}

__global__ __launch_bounds__(256) void k_scan_add() {
  int i = blockIdx.x * 256 + threadIdx.x;
  if (i >= NN) return;
  int r = g_rowptr[i] + g_blocksum[blockIdx.x];
  g_rowptr[i] = r;
  g_cur[i] = r;
}

__global__ __launch_bounds__(256) void k_scatter(const int* __restrict__ ei) {
  int i = blockIdx.x * 256 + threadIdx.x;
  if (i >= ETOT) return;
  int s, d;
  if (i < EE) { s = ei[i]; d = ei[EE + i]; } else { s = d = i - EE; }
  int pos = atomicAdd(&g_cur[d], 1);
  g_colsrc[pos] = s;
}

// ---------------- fp32 -> bf16 hi/lo split -----------------------------------
__global__ __launch_bounds__(256) void k_split(int sel, const float* __restrict__ xin) {
  int total = sel ? NN * FF : NN * FIN;
  const float* src = sel ? g_bufB : xin;
  unsigned short* oh = sel ? g_featHi : g_xHi;
  unsigned short* ol = sel ? g_featLo : g_xLo;
  int n4 = total >> 2;
  const float4* s4 = (const float4*)src;
  ushort4* oh4 = (ushort4*)oh;
  ushort4* ol4 = (ushort4*)ol;
  for (int i = blockIdx.x * blockDim.x + threadIdx.x; i < n4; i += gridDim.x * blockDim.x) {
    float4 v = s4[i];
    ushort4 h, l;
    h.x = f2bf(v.x); l.x = f2bf(v.x - bf2f(h.x));
    h.y = f2bf(v.y); l.y = f2bf(v.y - bf2f(h.y));
    h.z = f2bf(v.z); l.z = f2bf(v.z - bf2f(h.z));
    h.w = f2bf(v.w); l.w = f2bf(v.w - bf2f(h.w));
    oh4[i] = h; ol4[i] = l;
  }
}

// ---------------- GEMM: bufA = A @ Wt^T (3-term bf16 split, fp32 acc) --------
__global__ __launch_bounds__(256) void k_gemm(int asel, int widx, int K) {
  __shared__ unsigned short lA[128 * 64];
  __shared__ unsigned short lB[128 * 64];
  const unsigned short* Ah = asel ? g_featHi : g_xHi;
  const unsigned short* Al = asel ? g_featLo : g_xLo;
  const unsigned short* Bh = g_WtHi[widx];
  const unsigned short* Bl = g_WtLo[widx];
  const int m0 = blockIdx.x * 128;
  const int n0 = blockIdx.y * 128;
  const int tid = threadIdx.x;
  const int wave = tid >> 6, lane = tid & 63;
  const int wm = wave >> 1, wn = wave & 1;
  const int srow = lane >> 3;        // row within 8-row chunk
  const int scol = (lane & 7) * 8;   // k-element offset

  f32x4 acc[4][4] = {};

  for (int t = 0; t < 3; ++t) {
    const unsigned short* Ap = (t == 1) ? Al : Ah;
    const unsigned short* Bp = (t == 2) ? Bl : Bh;
    for (int k0 = 0; k0 < K; k0 += 64) {
      __syncthreads();  // prior reads done before overwrite
      #pragma unroll
      for (int it = 0; it < 4; ++it) {
        int c = wave * 4 + it;
        int rA = c * 8 + srow;
        int gr = m0 + rA; gr = (gr < NN) ? gr : (NN - 1);
        gl_lds16(Ap + (size_t)gr * K + k0 + scol, (unsigned short*)lA + c * 512);
        int cB = n0 + rA;  // always < 384
        gl_lds16(Bp + (size_t)cB * K + k0 + scol, (unsigned short*)lB + c * 512);
      }
      __syncthreads();  // drains vmcnt for global_load_lds
      #pragma unroll
      for (int kk = 0; kk < 64; kk += 32) {
        const int kb = kk + (lane >> 4) * 8;
        const int r16 = lane & 15;
        short8 af[4], bfr[4];
        #pragma unroll
        for (int mf = 0; mf < 4; ++mf)
          af[mf] = *(const short8*)&lA[(wm * 64 + mf * 16 + r16) * 64 + kb];
        #pragma unroll
        for (int nf = 0; nf < 4; ++nf)
          bfr[nf] = *(const short8*)&lB[(wn * 64 + nf * 16 + r16) * 64 + kb];
        #pragma unroll
        for (int mf = 0; mf < 4; ++mf)
          #pragma unroll
          for (int nf = 0; nf < 4; ++nf)
            mfma_acc(acc[mf][nf], af[mf], bfr[nf]);
      }
    }
  }
  asm volatile("s_nop 7\n\ts_nop 7" :::);
  #pragma unroll
  for (int mf = 0; mf < 4; ++mf) {
    #pragma unroll
    for (int nf = 0; nf < 4; ++nf) {
      int col = n0 + wn * 64 + nf * 16 + (lane & 15);
      int rb = m0 + wm * 64 + mf * 16 + ((lane >> 4) << 2);
      #pragma unroll
      for (int j = 0; j < 4; ++j) {
        int r = rb + j;
        if (r < NN) g_bufA[(size_t)r * FF + col] = acc[mf][nf][j];
      }
    }
  }
}

// ---------------- per-node attention coefficients ----------------------------
__global__ __launch_bounds__(256) void k_alpha(const float* __restrict__ asr,
                                               const float* __restrict__ adt) {
  int node = blockIdx.x * 4 + (threadIdx.x >> 6);
  int lane = threadIdx.x & 63;
  if (node >= NN) return;
  const float* hrow = g_bufA + (size_t)node * FF;
  #pragma unroll
  for (int h = 0; h < NH; ++h) {
    float v = hrow[h * 64 + lane];
    float ps = v * asr[h * 64 + lane];
    float pd = v * adt[h * 64 + lane];
    #pragma unroll
    for (int off = 32; off > 0; off >>= 1) {
      ps += __shfl_down(ps, off);
      pd += __shfl_down(pd, off);
    }
    if (lane == 0) { g_alS[node * NH + h] = ps; g_alD[node * NH + h] = pd; }
  }
}

// ---------------- softmax + aggregation, one wave per destination node -------
__global__ __launch_bounds__(256) void k_edge(const float* __restrict__ bias, int outsel) {
  float* out = outsel ? g_bufC : g_bufB;
  int node = blockIdx.x * 4 + (threadIdx.x >> 6);
  int lane = threadIdx.x & 63;
  if (node >= NN) return;
  const int lo = g_rowptr[node], hi = g_rowptr[node + 1];
  float ad[NH];
  #pragma unroll
  for (int h = 0; h < NH; ++h) ad[h] = g_alD[node * NH + h];
  float m[NH];
  #pragma unroll
  for (int h = 0; h < NH; ++h) m[h] = -1e30f;
  // pass 1: wave-parallel max per head
  for (int e = lo + lane; e < hi; e += 64) {
    int s = g_colsrc[e];
    #pragma unroll
    for (int h = 0; h < NH; ++h) {
      float v = g_alS[s * NH + h] + ad[h];
      v = (v > 0.f) ? v : NEG * v;
      m[h] = fmaxf(m[h], v);
    }
  }
  #pragma unroll
  for (int h = 0; h < NH; ++h)
    #pragma unroll
    for (int off = 32; off > 0; off >>= 1)
      m[h] = fmaxf(m[h], __shfl_xor(m[h], off));
  // pass 2: un-normalized weighted aggregation + denominator
  float acc[NH] = {0.f, 0.f, 0.f, 0.f, 0.f, 0.f};
  float ssum[NH] = {0.f, 0.f, 0.f, 0.f, 0.f, 0.f};
  for (int e = lo; e < hi; ++e) {
    int s = g_colsrc[e];
    const float* hrow = g_bufA + (size_t)s * FF;
    #pragma unroll
    for (int h = 0; h < NH; ++h) {
      float v = g_alS[s * NH + h] + ad[h];
      v = (v > 0.f) ? v : NEG * v;
      float w = __expf(v - m[h]);
      ssum[h] += w;
      acc[h] = fmaf(w, hrow[h * 64 + lane], acc[h]);
    }
  }
  #pragma unroll
  for (int h = 0; h < NH; ++h) {
    float o = acc[h] / (ssum[h] + 1e-16f) + bias[h * 64 + lane];
    out[(size_t)node * FF + h * 64 + lane] = fmaxf(o, 0.f);
  }
}

// ---------------- pooling: segmented accumulation over sorted batch ----------
__global__ __launch_bounds__(384) void k_pool_acc(const int* __restrict__ batch) {
  int n0 = blockIdx.x * PCH;
  if (n0 >= NN) return;
  int n1 = n0 + PCH; if (n1 > NN) n1 = NN;
  int d = threadIdx.x;
  int cur = batch[n0];
  float acc = 0.f;
  int cnt = 0;
  for (int n = n0; n < n1; ++n) {
    int g = batch[n];
    if (g != cur) {
      atomicAdd(&g_pool[cur * FF + d], acc);
      if (d == 0) atomicAdd(&g_gcnt[cur], cnt);
      acc = 0.f; cnt = 0; cur = g;
    }
    acc += g_bufB[(size_t)n * FF + d] + g_bufC[(size_t)n * FF + d];
    ++cnt;
  }
  atomicAdd(&g_pool[cur * FF + d], acc);
  if (d == 0) atomicAdd(&g_gcnt[cur], cnt);
}

// ---------------- finish: mean + readout MLP (fused) -------------------------
__global__ __launch_bounds__(384) void k_finish(const float* __restrict__ r1w,
                                                const float* __restrict__ r1b,
                                                const float* __restrict__ r2w,
                                                const float* __restrict__ r2b,
                                                float* __restrict__ dout) {
  int g = blockIdx.x;
  int d = threadIdx.x;
  __shared__ float xr[FF];
  __shared__ float hid[64];
  int cnt = g_gcnt[g];
  float denom = (cnt > 0) ? (float)cnt : 1.f;
  float v = g_pool[g * FF + d] / denom;
  xr[d] = v;
  dout[NG * NOUT + g * FF + d] = v;
  __syncthreads();
  if (d < 64) {
    float acc = r1b[d];
    for (int k = 0; k < FF; ++k) acc = fmaf(xr[k], r1w[k * 64 + d], acc);
    hid[d] = fmaxf(acc, 0.f);
  }
  __syncthreads();
  if (d < NOUT) {
    float o = r2b[d];
    #pragma unroll
    for (int j = 0; j < 64; ++j) o = fmaf(hid[j], r2w[j * NOUT + d], o);
    dout[g * NOUT + d] = o;
  }
}

// ---------------- orchestration ----------------------------------------------
extern "C" void kernel_launch(void* const* d_in, const int* in_sizes, int n_in,
                              void* d_out, int out_size, void* d_ws, size_t ws_size,
                              hipStream_t stream) {
  const float* x    = (const float*)d_in[0];
  const int* ei     = (const int*)d_in[1];
  const int* batch  = (const int*)d_in[2];
  const float* W1   = (const float*)d_in[3];
  const float* a1s  = (const float*)d_in[4];
  const float* a1d  = (const float*)d_in[5];
  const float* b1   = (const float*)d_in[6];
  const float* W2   = (const float*)d_in[7];
  const float* a2s  = (const float*)d_in[8];
  const float* a2d  = (const float*)d_in[9];
  const float* b2   = (const float*)d_in[10];
  const float* Ws1  = (const float*)d_in[11];
  const float* as1s = (const float*)d_in[12];
  const float* as1d = (const float*)d_in[13];
  const float* bs1  = (const float*)d_in[14];
  const float* Ws2  = (const float*)d_in[15];
  const float* as2s = (const float*)d_in[16];
  const float* as2d = (const float*)d_in[17];
  const float* bs2  = (const float*)d_in[18];
  const float* r1w  = (const float*)d_in[19];
  const float* r1b  = (const float*)d_in[20];
  const float* r2w  = (const float*)d_in[21];
  const float* r2b  = (const float*)d_in[22];
  float* out = (float*)d_out;

  dim3 b256(256);
  // weight prep (widx: 0=Ws1, 1=Ws2, 2=W1, 3=W2)
  k_wprep<<<dim3((FIN * FF + 255) / 256), b256, 0, stream>>>(Ws1, FIN, 0);
  k_wprep<<<dim3((FF * FF + 255) / 256), b256, 0, stream>>>(Ws2, FF, 1);
  k_wprep<<<dim3((FIN * FF + 255) / 256), b256, 0, stream>>>(W1, FIN, 2);
  k_wprep<<<dim3((FF * FF + 255) / 256), b256, 0, stream>>>(W2, FF, 3);
  // zero (CSR histogram + pool accumulators)
  k_zero<<<dim3((NG * FF + 255) / 256), b256, 0, stream>>>();
  k_hist<<<dim3((ETOT + 255) / 256), b256, 0, stream>>>(ei);
  // hierarchical scan
  k_scan_blk<<<dim3(NB), b256, 0, stream>>>();
  k_scan_top<<<dim3(1), dim3(128), 0, stream>>>();
  k_scan_add<<<dim3(NB), b256, 0, stream>>>();
  k_scatter<<<dim3((ETOT + 255) / 256), b256, 0, stream>>>(ei);
  // split x once (reused by both branch-1 convs)
  k_split<<<dim3(2048), b256, 0, stream>>>(0, x);

  dim3 gemmGrid((NN + 127) / 128, FF / 128);
  dim3 nodeGrid((NN + 3) / 4);

  // skip branch, layer 1: bufB = relu(conv(x, Ws1))
  k_gemm<<<gemmGrid, b256, 0, stream>>>(0, 0, FIN);
  k_alpha<<<nodeGrid, b256, 0, stream>>>(as1s, as1d);
  k_edge<<<nodeGrid, b256, 0, stream>>>(bs1, 0);
  // skip branch, layer 2: bufC = relu(conv(bufB, Ws2))
  k_split<<<dim3(2048), b256, 0, stream>>>(1, nullptr);
  k_gemm<<<gemmGrid, b256, 0, stream>>>(1, 1, FF);
  k_alpha<<<nodeGrid, b256, 0, stream>>>(as2s, as2d);
  k_edge<<<nodeGrid, b256, 0, stream>>>(bs2, 1);
  // main branch, layer 1: bufB = relu(conv(x, W1))
  k_gemm<<<gemmGrid, b256, 0, stream>>>(0, 2, FIN);
  k_alpha<<<nodeGrid, b256, 0, stream>>>(a1s, a1d);
  k_edge<<<nodeGrid, b256, 0, stream>>>(b1, 0);
  // main branch, layer 2: bufB = relu(conv(bufB, W2))
  k_split<<<dim3(2048), b256, 0, stream>>>(1, nullptr);
  k_gemm<<<gemmGrid, b256, 0, stream>>>(1, 3, FF);
  k_alpha<<<nodeGrid, b256, 0, stream>>>(a2s, a2d);
  k_edge<<<nodeGrid, b256, 0, stream>>>(b2, 0);
  // pool (bufB + bufC) and readout
  k_pool_acc<<<dim3((NN + PCH - 1) / PCH), dim3(384), 0, stream>>>(batch);
  k_finish<<<dim3(NG), dim3(384), 0, stream>>>(r1w, r1b, r2w, r2b, out);
}

// Round 6
// 510.500 us; speedup vs baseline: 1.5615x; 1.2251x over previous
//
#include <hip/hip_runtime.h>
#include <hip/hip_fp16.h>

#define NN 20000
#define EE 320000
#define ETOT 340000
#define FIN 128
#define NH 6
#define FF 384
#define NOUT 10
#define NG 64
#define NEG 0.2f
#define PCH 32
#define NB ((NN + 255) / 256)

typedef short short8 __attribute__((ext_vector_type(8)));
typedef float f32x4 __attribute__((ext_vector_type(4)));

// ---------------- static device storage (avoids ws_size dependence) ----------
__device__ __half g_h16[(size_t)NN * FF];   // gemm output h (fp16 gather table)
__device__ float g_bufB[(size_t)NN * FF];   // conv output / layer input
__device__ float g_bufC[(size_t)NN * FF];   // xs2 storage
__device__ unsigned short g_featHi[(size_t)NN * FF];
__device__ unsigned short g_featLo[(size_t)NN * FF];
__device__ unsigned short g_xHi[(size_t)NN * FIN];
__device__ unsigned short g_xLo[(size_t)NN * FIN];
__device__ unsigned short g_WtHi[4][FF * FF];  // transposed weights [col][k]
__device__ unsigned short g_WtLo[4][FF * FF];
__device__ float g_alS[NN * NH];
__device__ float g_alD[NN * NH];
__device__ int g_rowptr[NN + 1];
__device__ int g_cnt[NN];
__device__ int g_cur[NN];
__device__ int g_blocksum[NB];
__device__ int g_colsrc[ETOT];
__device__ float g_pool[NG * FF];
__device__ int g_gcnt[NG];

// ---------------- helpers ----------------------------------------------------
__device__ __forceinline__ unsigned short f2bf(float f) {
  unsigned u = __float_as_uint(f);
  u += 0x7FFFu + ((u >> 16) & 1u);
  return (unsigned short)(u >> 16);
}
__device__ __forceinline__ float bf2f(unsigned short s) {
  return __uint_as_float(((unsigned)s) << 16);
}

__device__ __forceinline__ void gl_lds16(const void* g, void* l) {
  __builtin_amdgcn_global_load_lds(
      (const __attribute__((address_space(1))) unsigned int*)(unsigned long long)g,
      (__attribute__((address_space(3))) unsigned int*)(unsigned int)(unsigned long long)l,
      16, 0, 0);
}

__device__ __forceinline__ void mfma_acc(f32x4& c, short8 a, short8 b) {
  asm("v_mfma_f32_16x16x32_bf16 %0, %1, %2, %0" : "+v"(c) : "v"(a), "v"(b));
}

// ---------------- weight prep: fp32 [K,F] -> bf16 hi/lo transposed [F][K] ----
__global__ __launch_bounds__(256) void k_wprep(const float* __restrict__ W, int K, int widx) {
  int i = blockIdx.x * 256 + threadIdx.x;
  if (i >= K * FF) return;
  int k = i / FF, c = i % FF;
  float v = W[i];
  unsigned short h = f2bf(v);
  g_WtHi[widx][c * K + k] = h;
  g_WtLo[widx][c * K + k] = f2bf(v - bf2f(h));
}

// ---------------- zero pass (CSR histogram + pool accumulators) --------------
__global__ __launch_bounds__(256) void k_zero() {
  int i = blockIdx.x * 256 + threadIdx.x;
  if (i < NN) g_cnt[i] = 0;
  if (i < NG * FF) g_pool[i] = 0.f;
  if (i < NG) g_gcnt[i] = 0;
}

__global__ __launch_bounds__(256) void k_hist(const int* __restrict__ ei) {
  int i = blockIdx.x * 256 + threadIdx.x;
  if (i >= ETOT) return;
  int d = (i < EE) ? ei[EE + i] : (i - EE);
  atomicAdd(&g_cnt[d], 1);
}

// ---------------- hierarchical scan (3 launches, shuffle-based) --------------
__global__ __launch_bounds__(256) void k_scan_blk() {
  int b = blockIdx.x;
  int tid = threadIdx.x;
  int i = b * 256 + tid;
  int lane = tid & 63, wid = tid >> 6;
  int v = (i < NN) ? g_cnt[i] : 0;
  int s = v;
  #pragma unroll
  for (int off = 1; off < 64; off <<= 1) {
    int t = __shfl_up(s, off);
    if (lane >= off) s += t;
  }
  __shared__ int wsum[4];
  if (lane == 63) wsum[wid] = s;
  __syncthreads();
  int woff = 0;
  #pragma unroll
  for (int w = 0; w < 4; ++w) woff += (w < wid) ? wsum[w] : 0;
  if (i < NN) g_rowptr[i] = woff + s - v;   // block-local exclusive
  if (tid == 0) g_blocksum[b] = wsum[0] + wsum[1] + wsum[2] + wsum[3];
}

__global__ __launch_bounds__(128) void k_scan_top() {
  int tid = threadIdx.x;
  int lane = tid & 63, wid = tid >> 6;
  int v = (tid < NB) ? g_blocksum[tid] : 0;
  int s = v;
  #pragma unroll
  for (int off = 1; off < 64; off <<= 1) {
    int t = __shfl_up(s, off);
    if (lane >= off) s += t;
  }
  __shared__ int wsum[2];
  if (lane == 63) wsum[wid] = s;
  __syncthreads();
  int woff = (wid == 1) ? wsum[0] : 0;
  int excl = woff + s - v;
  if (tid < NB) g_blocksum[tid] = excl;
  if (tid == NB - 1) g_rowptr[NN] = excl + v;
}

__global__ __launch_bounds__(256) void k_scan_add() {
  int i = blockIdx.x * 256 + threadIdx.x;
  if (i >= NN) return;
  int r = g_rowptr[i] + g_blocksum[blockIdx.x];
  g_rowptr[i] = r;
  g_cur[i] = r;
}

__global__ __launch_bounds__(256) void k_scatter(const int* __restrict__ ei) {
  int i = blockIdx.x * 256 + threadIdx.x;
  if (i >= ETOT) return;
  int s, d;
  if (i < EE) { s = ei[i]; d = ei[EE + i]; } else { s = d = i - EE; }
  int pos = atomicAdd(&g_cur[d], 1);
  g_colsrc[pos] = s;
}

// ---------------- fp32 -> bf16 hi/lo split -----------------------------------
__global__ __launch_bounds__(256) void k_split(int sel, const float* __restrict__ xin) {
  int total = sel ? NN * FF : NN * FIN;
  const float* src = sel ? g_bufB : xin;
  unsigned short* oh = sel ? g_featHi : g_xHi;
  unsigned short* ol = sel ? g_featLo : g_xLo;
  int n4 = total >> 2;
  const float4* s4 = (const float4*)src;
  ushort4* oh4 = (ushort4*)oh;
  ushort4* ol4 = (ushort4*)ol;
  for (int i = blockIdx.x * blockDim.x + threadIdx.x; i < n4; i += gridDim.x * blockDim.x) {
    float4 v = s4[i];
    ushort4 h, l;
    h.x = f2bf(v.x); l.x = f2bf(v.x - bf2f(h.x));
    h.y = f2bf(v.y); l.y = f2bf(v.y - bf2f(h.y));
    h.z = f2bf(v.z); l.z = f2bf(v.z - bf2f(h.z));
    h.w = f2bf(v.w); l.w = f2bf(v.w - bf2f(h.w));
    oh4[i] = h; ol4[i] = l;
  }
}

// ---------------- GEMM: h16 = A @ Wt^T (3-term bf16 split, fp32 acc) ---------
__global__ __launch_bounds__(256) void k_gemm(int asel, int widx, int K) {
  __shared__ unsigned short lA[128 * 64];
  __shared__ unsigned short lB[128 * 64];
  const unsigned short* Ah = asel ? g_featHi : g_xHi;
  const unsigned short* Al = asel ? g_featLo : g_xLo;
  const unsigned short* Bh = g_WtHi[widx];
  const unsigned short* Bl = g_WtLo[widx];
  const int m0 = blockIdx.x * 128;
  const int n0 = blockIdx.y * 128;
  const int tid = threadIdx.x;
  const int wave = tid >> 6, lane = tid & 63;
  const int wm = wave >> 1, wn = wave & 1;
  const int srow = lane >> 3;        // row within 8-row chunk
  const int scol = (lane & 7) * 8;   // k-element offset

  f32x4 acc[4][4] = {};

  for (int t = 0; t < 3; ++t) {
    const unsigned short* Ap = (t == 1) ? Al : Ah;
    const unsigned short* Bp = (t == 2) ? Bl : Bh;
    for (int k0 = 0; k0 < K; k0 += 64) {
      __syncthreads();  // prior reads done before overwrite
      #pragma unroll
      for (int it = 0; it < 4; ++it) {
        int c = wave * 4 + it;
        int rA = c * 8 + srow;
        int gr = m0 + rA; gr = (gr < NN) ? gr : (NN - 1);
        gl_lds16(Ap + (size_t)gr * K + k0 + scol, (unsigned short*)lA + c * 512);
        int cB = n0 + rA;  // always < 384
        gl_lds16(Bp + (size_t)cB * K + k0 + scol, (unsigned short*)lB + c * 512);
      }
      __syncthreads();  // drains vmcnt for global_load_lds
      #pragma unroll
      for (int kk = 0; kk < 64; kk += 32) {
        const int kb = kk + (lane >> 4) * 8;
        const int r16 = lane & 15;
        short8 af[4], bfr[4];
        #pragma unroll
        for (int mf = 0; mf < 4; ++mf)
          af[mf] = *(const short8*)&lA[(wm * 64 + mf * 16 + r16) * 64 + kb];
        #pragma unroll
        for (int nf = 0; nf < 4; ++nf)
          bfr[nf] = *(const short8*)&lB[(wn * 64 + nf * 16 + r16) * 64 + kb];
        #pragma unroll
        for (int mf = 0; mf < 4; ++mf)
          #pragma unroll
          for (int nf = 0; nf < 4; ++nf)
            mfma_acc(acc[mf][nf], af[mf], bfr[nf]);
      }
    }
  }
  asm volatile("s_nop 7\n\ts_nop 7" :::);
  #pragma unroll
  for (int mf = 0; mf < 4; ++mf) {
    #pragma unroll
    for (int nf = 0; nf < 4; ++nf) {
      int col = n0 + wn * 64 + nf * 16 + (lane & 15);
      int rb = m0 + wm * 64 + mf * 16 + ((lane >> 4) << 2);
      #pragma unroll
      for (int j = 0; j < 4; ++j) {
        int r = rb + j;
        if (r < NN) g_h16[(size_t)r * FF + col] = __float2half(acc[mf][nf][j]);
      }
    }
  }
}

// ---------------- per-node attention coefficients (fp16 h-table) -------------
__global__ __launch_bounds__(256) void k_alpha(const float* __restrict__ asr,
                                               const float* __restrict__ adt) {
  int node = blockIdx.x * 4 + (threadIdx.x >> 6);
  int lane = threadIdx.x & 63;
  if (node >= NN) return;
  const __half* hrow = g_h16 + (size_t)node * FF;
  #pragma unroll
  for (int h = 0; h < NH; ++h) {
    float v = __half2float(hrow[h * 64 + lane]);
    float ps = v * asr[h * 64 + lane];
    float pd = v * adt[h * 64 + lane];
    #pragma unroll
    for (int off = 32; off > 0; off >>= 1) {
      ps += __shfl_down(ps, off);
      pd += __shfl_down(pd, off);
    }
    if (lane == 0) { g_alS[node * NH + h] = ps; g_alD[node * NH + h] = pd; }
  }
}

// ---------------- softmax + aggregation, one wave per destination node -------
// fast path (deg<=64): lane-parallel softmax, w broadcast via shfl in pass 2.
// gather reads packed __half2 (3 dwords per edge per lane).
__global__ __launch_bounds__(256) void k_edge(const float* __restrict__ bias, int outsel) {
  float* out = outsel ? g_bufC : g_bufB;
  int node = blockIdx.x * 4 + (threadIdx.x >> 6);
  int lane = threadIdx.x & 63;
  if (node >= NN) return;
  const int lo = g_rowptr[node], hi = g_rowptr[node + 1];
  const int deg = hi - lo;
  float ad[NH];
  #pragma unroll
  for (int h = 0; h < NH; ++h) ad[h] = g_alD[node * NH + h];

  float w[NH];      // this lane's edge weights (fast path)
  float m[NH];
  float ssum[NH];
  const bool fast = (deg <= 64);

  if (fast) {
    // one edge per lane, fully parallel softmax
    bool val = lane < deg;
    int s = val ? g_colsrc[lo + lane] : 0;
    const float2* ap = (const float2*)(g_alS + (size_t)s * NH);
    float2 p0 = ap[0], p1 = ap[1], p2 = ap[2];
    float v[NH] = {p0.x + ad[0], p0.y + ad[1], p1.x + ad[2],
                   p1.y + ad[3], p2.x + ad[4], p2.y + ad[5]};
    #pragma unroll
    for (int h = 0; h < NH; ++h) {
      v[h] = (v[h] > 0.f) ? v[h] : NEG * v[h];
      m[h] = val ? v[h] : -1e30f;
    }
    #pragma unroll
    for (int h = 0; h < NH; ++h)
      #pragma unroll
      for (int off = 32; off > 0; off >>= 1)
        m[h] = fmaxf(m[h], __shfl_xor(m[h], off));
    #pragma unroll
    for (int h = 0; h < NH; ++h) {
      w[h] = val ? __expf(v[h] - m[h]) : 0.f;
      ssum[h] = w[h];
    }
    #pragma unroll
    for (int h = 0; h < NH; ++h)
      #pragma unroll
      for (int off = 32; off > 0; off >>= 1)
        ssum[h] += __shfl_xor(ssum[h], off);
  } else {
    // generic slow path (wave-uniform branch; rare)
    #pragma unroll
    for (int h = 0; h < NH; ++h) m[h] = -1e30f;
    for (int e = lo + lane; e < hi; e += 64) {
      int s = g_colsrc[e];
      #pragma unroll
      for (int h = 0; h < NH; ++h) {
        float v = g_alS[s * NH + h] + ad[h];
        v = (v > 0.f) ? v : NEG * v;
        m[h] = fmaxf(m[h], v);
      }
    }
    #pragma unroll
    for (int h = 0; h < NH; ++h)
      #pragma unroll
      for (int off = 32; off > 0; off >>= 1)
        m[h] = fmaxf(m[h], __shfl_xor(m[h], off));
    #pragma unroll
    for (int h = 0; h < NH; ++h) ssum[h] = 0.f;
    for (int e = lo + lane; e < hi; e += 64) {
      int s = g_colsrc[e];
      #pragma unroll
      for (int h = 0; h < NH; ++h) {
        float v = g_alS[s * NH + h] + ad[h];
        v = (v > 0.f) ? v : NEG * v;
        ssum[h] += __expf(v - m[h]);
      }
    }
    #pragma unroll
    for (int h = 0; h < NH; ++h)
      #pragma unroll
      for (int off = 32; off > 0; off >>= 1)
        ssum[h] += __shfl_xor(ssum[h], off);
  }

  // pass 2: weighted aggregation. lane owns dims {c*128+2*lane, +1}, c=0..2.
  // head of chunk c for this lane: 2c + (lane>>5)  -> select, static indexing.
  float2 acc[3] = {{0.f, 0.f}, {0.f, 0.f}, {0.f, 0.f}};
  const bool hiHalf = (lane >= 32);
  for (int e = lo; e < hi; ++e) {
    int s = g_colsrc[e];
    const __half2* row = (const __half2*)(g_h16 + (size_t)s * FF);
    float wa[3];
    if (fast) {
      int ei = e - lo;
      float w0 = __shfl(w[0], ei), w1 = __shfl(w[1], ei);
      float w2 = __shfl(w[2], ei), w3 = __shfl(w[3], ei);
      float w4 = __shfl(w[4], ei), w5 = __shfl(w[5], ei);
      wa[0] = hiHalf ? w1 : w0;
      wa[1] = hiHalf ? w3 : w2;
      wa[2] = hiHalf ? w5 : w4;
    } else {
      const float* as = g_alS + (size_t)s * NH;
      float we[NH];
      #pragma unroll
      for (int h = 0; h < NH; ++h) {
        float v = as[h] + ad[h];
        v = (v > 0.f) ? v : NEG * v;
        we[h] = __expf(v - m[h]);
      }
      wa[0] = hiHalf ? we[1] : we[0];
      wa[1] = hiHalf ? we[3] : we[2];
      wa[2] = hiHalf ? we[5] : we[4];
    }
    #pragma unroll
    for (int c = 0; c < 3; ++c) {
      float2 hv = __half22float2(row[c * 64 + lane]);
      acc[c].x = fmaf(wa[c], hv.x, acc[c].x);
      acc[c].y = fmaf(wa[c], hv.y, acc[c].y);
    }
  }

  #pragma unroll
  for (int c = 0; c < 3; ++c) {
    float sden = (hiHalf ? ssum[2 * c + 1] : ssum[2 * c]) + 1e-16f;
    float2 bv = *(const float2*)(bias + c * 128 + lane * 2);
    float2 o;
    o.x = fmaxf(acc[c].x / sden + bv.x, 0.f);
    o.y = fmaxf(acc[c].y / sden + bv.y, 0.f);
    *(float2*)(out + (size_t)node * FF + c * 128 + lane * 2) = o;
  }
}

// ---------------- pooling: segmented accumulation over sorted batch ----------
__global__ __launch_bounds__(384) void k_pool_acc(const int* __restrict__ batch) {
  int n0 = blockIdx.x * PCH;
  if (n0 >= NN) return;
  int n1 = n0 + PCH; if (n1 > NN) n1 = NN;
  int d = threadIdx.x;
  int cur = batch[n0];
  float acc = 0.f;
  int cnt = 0;
  for (int n = n0; n < n1; ++n) {
    int g = batch[n];
    if (g != cur) {
      atomicAdd(&g_pool[cur * FF + d], acc);
      if (d == 0) atomicAdd(&g_gcnt[cur], cnt);
      acc = 0.f; cnt = 0; cur = g;
    }
    acc += g_bufB[(size_t)n * FF + d] + g_bufC[(size_t)n * FF + d];
    ++cnt;
  }
  atomicAdd(&g_pool[cur * FF + d], acc);
  if (d == 0) atomicAdd(&g_gcnt[cur], cnt);
}

// ---------------- finish: mean + readout MLP (fused) -------------------------
__global__ __launch_bounds__(384) void k_finish(const float* __restrict__ r1w,
                                                const float* __restrict__ r1b,
                                                const float* __restrict__ r2w,
                                                const float* __restrict__ r2b,
                                                float* __restrict__ dout) {
  int g = blockIdx.x;
  int d = threadIdx.x;
  __shared__ float xr[FF];
  __shared__ float hid[64];
  int cnt = g_gcnt[g];
  float denom = (cnt > 0) ? (float)cnt : 1.f;
  float v = g_pool[g * FF + d] / denom;
  xr[d] = v;
  dout[NG * NOUT + g * FF + d] = v;
  __syncthreads();
  if (d < 64) {
    float acc = r1b[d];
    for (int k = 0; k < FF; ++k) acc = fmaf(xr[k], r1w[k * 64 + d], acc);
    hid[d] = fmaxf(acc, 0.f);
  }
  __syncthreads();
  if (d < NOUT) {
    float o = r2b[d];
    #pragma unroll
    for (int j = 0; j < 64; ++j) o = fmaf(hid[j], r2w[j * NOUT + d], o);
    dout[g * NOUT + d] = o;
  }
}

// ---------------- orchestration ----------------------------------------------
extern "C" void kernel_launch(void* const* d_in, const int* in_sizes, int n_in,
                              void* d_out, int out_size, void* d_ws, size_t ws_size,
                              hipStream_t stream) {
  const float* x    = (const float*)d_in[0];
  const int* ei     = (const int*)d_in[1];
  const int* batch  = (const int*)d_in[2];
  const float* W1   = (const float*)d_in[3];
  const float* a1s  = (const float*)d_in[4];
  const float* a1d  = (const float*)d_in[5];
  const float* b1   = (const float*)d_in[6];
  const float* W2   = (const float*)d_in[7];
  const float* a2s  = (const float*)d_in[8];
  const float* a2d  = (const float*)d_in[9];
  const float* b2   = (const float*)d_in[10];
  const float* Ws1  = (const float*)d_in[11];
  const float* as1s = (const float*)d_in[12];
  const float* as1d = (const float*)d_in[13];
  const float* bs1  = (const float*)d_in[14];
  const float* Ws2  = (const float*)d_in[15];
  const float* as2s = (const float*)d_in[16];
  const float* as2d = (const float*)d_in[17];
  const float* bs2  = (const float*)d_in[18];
  const float* r1w  = (const float*)d_in[19];
  const float* r1b  = (const float*)d_in[20];
  const float* r2w  = (const float*)d_in[21];
  const float* r2b  = (const float*)d_in[22];
  float* out = (float*)d_out;

  dim3 b256(256);
  // weight prep (widx: 0=Ws1, 1=Ws2, 2=W1, 3=W2)
  k_wprep<<<dim3((FIN * FF + 255) / 256), b256, 0, stream>>>(Ws1, FIN, 0);
  k_wprep<<<dim3((FF * FF + 255) / 256), b256, 0, stream>>>(Ws2, FF, 1);
  k_wprep<<<dim3((FIN * FF + 255) / 256), b256, 0, stream>>>(W1, FIN, 2);
  k_wprep<<<dim3((FF * FF + 255) / 256), b256, 0, stream>>>(W2, FF, 3);
  // zero (CSR histogram + pool accumulators)
  k_zero<<<dim3((NG * FF + 255) / 256), b256, 0, stream>>>();
  k_hist<<<dim3((ETOT + 255) / 256), b256, 0, stream>>>(ei);
  // hierarchical scan
  k_scan_blk<<<dim3(NB), b256, 0, stream>>>();
  k_scan_top<<<dim3(1), dim3(128), 0, stream>>>();
  k_scan_add<<<dim3(NB), b256, 0, stream>>>();
  k_scatter<<<dim3((ETOT + 255) / 256), b256, 0, stream>>>(ei);
  // split x once (reused by both branch-1 convs)
  k_split<<<dim3(2048), b256, 0, stream>>>(0, x);

  dim3 gemmGrid((NN + 127) / 128, FF / 128);
  dim3 nodeGrid((NN + 3) / 4);

  // skip branch, layer 1: bufB = relu(conv(x, Ws1))
  k_gemm<<<gemmGrid, b256, 0, stream>>>(0, 0, FIN);
  k_alpha<<<nodeGrid, b256, 0, stream>>>(as1s, as1d);
  k_edge<<<nodeGrid, b256, 0, stream>>>(bs1, 0);
  // skip branch, layer 2: bufC = relu(conv(bufB, Ws2))
  k_split<<<dim3(2048), b256, 0, stream>>>(1, nullptr);
  k_gemm<<<gemmGrid, b256, 0, stream>>>(1, 1, FF);
  k_alpha<<<nodeGrid, b256, 0, stream>>>(as2s, as2d);
  k_edge<<<nodeGrid, b256, 0, stream>>>(bs2, 1);
  // main branch, layer 1: bufB = relu(conv(x, W1))
  k_gemm<<<gemmGrid, b256, 0, stream>>>(0, 2, FIN);
  k_alpha<<<nodeGrid, b256, 0, stream>>>(a1s, a1d);
  k_edge<<<nodeGrid, b256, 0, stream>>>(b1, 0);
  // main branch, layer 2: bufB = relu(conv(bufB, W2))
  k_split<<<dim3(2048), b256, 0, stream>>>(1, nullptr);
  k_gemm<<<gemmGrid, b256, 0, stream>>>(1, 3, FF);
  k_alpha<<<nodeGrid, b256, 0, stream>>>(a2s, a2d);
  k_edge<<<nodeGrid, b256, 0, stream>>>(b2, 0);
  // pool (bufB + bufC) and readout
  k_pool_acc<<<dim3((NN + PCH - 1) / PCH), dim3(384), 0, stream>>>(batch);
  k_finish<<<dim3(NG), dim3(384), 0, stream>>>(r1w, r1b, r2w, r2b, out);
}

// Round 7
// 448.952 us; speedup vs baseline: 1.7756x; 1.1371x over previous
//
#include <hip/hip_runtime.h>
#include <hip/hip_fp16.h>

#define NN 20000
#define EE 320000
#define ETOT 340000
#define FIN 128
#define NH 6
#define FF 384
#define NOUT 10
#define NG 64
#define NEG 0.2f
#define PCH 32
#define NB ((NN + 255) / 256)

typedef short short8 __attribute__((ext_vector_type(8)));
typedef float f32x4 __attribute__((ext_vector_type(4)));

// ---------------- static device storage (avoids ws_size dependence) ----------
__device__ __half g_h16[(size_t)NN * FF];   // gemm output h (fp16 gather table)
__device__ float g_bufB[(size_t)NN * FF];   // conv output / layer input
__device__ float g_bufC[(size_t)NN * FF];   // xs2 storage
__device__ unsigned short g_featHi[(size_t)NN * FF];
__device__ unsigned short g_featLo[(size_t)NN * FF];
__device__ unsigned short g_xHi[(size_t)NN * FIN];
__device__ unsigned short g_xLo[(size_t)NN * FIN];
__device__ unsigned short g_WtHi[4][FF * FF];  // transposed weights [col][k]
__device__ unsigned short g_WtLo[4][FF * FF];
__device__ float g_alS[NN * NH];
__device__ float g_alD[NN * NH];
__device__ int g_rowptr[NN + 1];
__device__ int g_cnt[NN];
__device__ int g_cur[NN];
__device__ int g_blocksum[NB];
__device__ int g_colsrc[ETOT];
__device__ float g_pool[NG * FF];
__device__ int g_gcnt[NG];

// ---------------- helpers ----------------------------------------------------
__device__ __forceinline__ unsigned short f2bf(float f) {
  unsigned u = __float_as_uint(f);
  u += 0x7FFFu + ((u >> 16) & 1u);
  return (unsigned short)(u >> 16);
}
__device__ __forceinline__ float bf2f(unsigned short s) {
  return __uint_as_float(((unsigned)s) << 16);
}

__device__ __forceinline__ void gl_lds16(const void* g, void* l) {
  __builtin_amdgcn_global_load_lds(
      (const __attribute__((address_space(1))) unsigned int*)(unsigned long long)g,
      (__attribute__((address_space(3))) unsigned int*)(unsigned int)(unsigned long long)l,
      16, 0, 0);
}

__device__ __forceinline__ void mfma_acc(f32x4& c, short8 a, short8 b) {
  asm("v_mfma_f32_16x16x32_bf16 %0, %1, %2, %0" : "+v"(c) : "v"(a), "v"(b));
}

// ---------------- weight prep: fp32 [K,F] -> bf16 hi/lo transposed [F][K] ----
__global__ __launch_bounds__(256) void k_wprep(const float* __restrict__ W, int K, int widx) {
  int i = blockIdx.x * 256 + threadIdx.x;
  if (i >= K * FF) return;
  int k = i / FF, c = i % FF;
  float v = W[i];
  unsigned short h = f2bf(v);
  g_WtHi[widx][c * K + k] = h;
  g_WtLo[widx][c * K + k] = f2bf(v - bf2f(h));
}

// ---------------- zero pass (CSR histogram + pool accumulators) --------------
__global__ __launch_bounds__(256) void k_zero() {
  int i = blockIdx.x * 256 + threadIdx.x;
  if (i < NN) g_cnt[i] = 0;
  if (i < NG * FF) g_pool[i] = 0.f;
  if (i < NG) g_gcnt[i] = 0;
}

__global__ __launch_bounds__(256) void k_hist(const int* __restrict__ ei) {
  int i = blockIdx.x * 256 + threadIdx.x;
  if (i >= ETOT) return;
  int d = (i < EE) ? ei[EE + i] : (i - EE);
  atomicAdd(&g_cnt[d], 1);
}

// ---------------- hierarchical scan (3 launches, shuffle-based) --------------
__global__ __launch_bounds__(256) void k_scan_blk() {
  int b = blockIdx.x;
  int tid = threadIdx.x;
  int i = b * 256 + tid;
  int lane = tid & 63, wid = tid >> 6;
  int v = (i < NN) ? g_cnt[i] : 0;
  int s = v;
  #pragma unroll
  for (int off = 1; off < 64; off <<= 1) {
    int t = __shfl_up(s, off);
    if (lane >= off) s += t;
  }
  __shared__ int wsum[4];
  if (lane == 63) wsum[wid] = s;
  __syncthreads();
  int woff = 0;
  #pragma unroll
  for (int w = 0; w < 4; ++w) woff += (w < wid) ? wsum[w] : 0;
  if (i < NN) g_rowptr[i] = woff + s - v;   // block-local exclusive
  if (tid == 0) g_blocksum[b] = wsum[0] + wsum[1] + wsum[2] + wsum[3];
}

__global__ __launch_bounds__(128) void k_scan_top() {
  int tid = threadIdx.x;
  int lane = tid & 63, wid = tid >> 6;
  int v = (tid < NB) ? g_blocksum[tid] : 0;
  int s = v;
  #pragma unroll
  for (int off = 1; off < 64; off <<= 1) {
    int t = __shfl_up(s, off);
    if (lane >= off) s += t;
  }
  __shared__ int wsum[2];
  if (lane == 63) wsum[wid] = s;
  __syncthreads();
  int woff = (wid == 1) ? wsum[0] : 0;
  int excl = woff + s - v;
  if (tid < NB) g_blocksum[tid] = excl;
  if (tid == NB - 1) g_rowptr[NN] = excl + v;
}

__global__ __launch_bounds__(256) void k_scan_add() {
  int i = blockIdx.x * 256 + threadIdx.x;
  if (i >= NN) return;
  int r = g_rowptr[i] + g_blocksum[blockIdx.x];
  g_rowptr[i] = r;
  g_cur[i] = r;
}

__global__ __launch_bounds__(256) void k_scatter(const int* __restrict__ ei) {
  int i = blockIdx.x * 256 + threadIdx.x;
  if (i >= ETOT) return;
  int s, d;
  if (i < EE) { s = ei[i]; d = ei[EE + i]; } else { s = d = i - EE; }
  int pos = atomicAdd(&g_cur[d], 1);
  g_colsrc[pos] = s;
}

// ---------------- fp32 -> bf16 hi/lo split (x input only) --------------------
__global__ __launch_bounds__(256) void k_split(const float* __restrict__ xin) {
  int n4 = (NN * FIN) >> 2;
  const float4* s4 = (const float4*)xin;
  ushort4* oh4 = (ushort4*)g_xHi;
  ushort4* ol4 = (ushort4*)g_xLo;
  for (int i = blockIdx.x * blockDim.x + threadIdx.x; i < n4; i += gridDim.x * blockDim.x) {
    float4 v = s4[i];
    ushort4 h, l;
    h.x = f2bf(v.x); l.x = f2bf(v.x - bf2f(h.x));
    h.y = f2bf(v.y); l.y = f2bf(v.y - bf2f(h.y));
    h.z = f2bf(v.z); l.z = f2bf(v.z - bf2f(h.z));
    h.w = f2bf(v.w); l.w = f2bf(v.w - bf2f(h.w));
    oh4[i] = h; ol4[i] = l;
  }
}

// ---------------- GEMM: h16 = A @ Wt^T (3-term bf16 split, fp32 acc) ---------
__global__ __launch_bounds__(256) void k_gemm(int asel, int widx, int K) {
  __shared__ unsigned short lA[128 * 64];
  __shared__ unsigned short lB[128 * 64];
  const unsigned short* Ah = asel ? g_featHi : g_xHi;
  const unsigned short* Al = asel ? g_featLo : g_xLo;
  const unsigned short* Bh = g_WtHi[widx];
  const unsigned short* Bl = g_WtLo[widx];
  const int m0 = blockIdx.x * 128;
  const int n0 = blockIdx.y * 128;
  const int tid = threadIdx.x;
  const int wave = tid >> 6, lane = tid & 63;
  const int wm = wave >> 1, wn = wave & 1;
  const int srow = lane >> 3;        // row within 8-row chunk
  const int scol = (lane & 7) * 8;   // k-element offset

  f32x4 acc[4][4] = {};

  for (int t = 0; t < 3; ++t) {
    const unsigned short* Ap = (t == 1) ? Al : Ah;
    const unsigned short* Bp = (t == 2) ? Bl : Bh;
    for (int k0 = 0; k0 < K; k0 += 64) {
      __syncthreads();  // prior reads done before overwrite
      #pragma unroll
      for (int it = 0; it < 4; ++it) {
        int c = wave * 4 + it;
        int rA = c * 8 + srow;
        int gr = m0 + rA; gr = (gr < NN) ? gr : (NN - 1);
        gl_lds16(Ap + (size_t)gr * K + k0 + scol, (unsigned short*)lA + c * 512);
        int cB = n0 + rA;  // always < 384
        gl_lds16(Bp + (size_t)cB * K + k0 + scol, (unsigned short*)lB + c * 512);
      }
      __syncthreads();  // drains vmcnt for global_load_lds
      #pragma unroll
      for (int kk = 0; kk < 64; kk += 32) {
        const int kb = kk + (lane >> 4) * 8;
        const int r16 = lane & 15;
        short8 af[4], bfr[4];
        #pragma unroll
        for (int mf = 0; mf < 4; ++mf)
          af[mf] = *(const short8*)&lA[(wm * 64 + mf * 16 + r16) * 64 + kb];
        #pragma unroll
        for (int nf = 0; nf < 4; ++nf)
          bfr[nf] = *(const short8*)&lB[(wn * 64 + nf * 16 + r16) * 64 + kb];
        #pragma unroll
        for (int mf = 0; mf < 4; ++mf)
          #pragma unroll
          for (int nf = 0; nf < 4; ++nf)
            mfma_acc(acc[mf][nf], af[mf], bfr[nf]);
      }
    }
  }
  asm volatile("s_nop 7\n\ts_nop 7" :::);
  #pragma unroll
  for (int mf = 0; mf < 4; ++mf) {
    #pragma unroll
    for (int nf = 0; nf < 4; ++nf) {
      int col = n0 + wn * 64 + nf * 16 + (lane & 15);
      int rb = m0 + wm * 64 + mf * 16 + ((lane >> 4) << 2);
      #pragma unroll
      for (int j = 0; j < 4; ++j) {
        int r = rb + j;
        if (r < NN) g_h16[(size_t)r * FF + col] = __float2half(acc[mf][nf][j]);
      }
    }
  }
}

// ---------------- per-node attention coefficients (fp16 h-table) -------------
__global__ __launch_bounds__(256) void k_alpha(const float* __restrict__ asr,
                                               const float* __restrict__ adt) {
  int node = blockIdx.x * 4 + (threadIdx.x >> 6);
  int lane = threadIdx.x & 63;
  if (node >= NN) return;
  const __half* hrow = g_h16 + (size_t)node * FF;
  #pragma unroll
  for (int h = 0; h < NH; ++h) {
    float v = __half2float(hrow[h * 64 + lane]);
    float ps = v * asr[h * 64 + lane];
    float pd = v * adt[h * 64 + lane];
    #pragma unroll
    for (int off = 32; off > 0; off >>= 1) {
      ps += __shfl_down(ps, off);
      pd += __shfl_down(pd, off);
    }
    if (lane == 0) { g_alS[node * NH + h] = ps; g_alD[node * NH + h] = pd; }
  }
}

// ---------------- softmax + aggregation, one wave per destination node -------
// fast path (deg<=64): lane-parallel softmax; normalized weights packed as
// __half2 and broadcast via 3 shfl/edge; edge loop unrolled x2 (two acc sets).
// mode: 0 -> float out to bufB; 1 -> float out to bufC; 2 -> bf16 hi/lo feat.
__global__ __launch_bounds__(256) void k_edge(const float* __restrict__ bias, int mode) {
  int node = blockIdx.x * 4 + (threadIdx.x >> 6);
  int lane = threadIdx.x & 63;
  if (node >= NN) return;
  const int lo = g_rowptr[node], hi = g_rowptr[node + 1];
  const int deg = hi - lo;
  float ad[NH];
  #pragma unroll
  for (int h = 0; h < NH; ++h) ad[h] = g_alD[node * NH + h];

  const bool hiHalf = (lane >= 32);
  int s = 0;                 // this lane's source (fast path)
  unsigned wpu[3];           // packed normalized weights {w0,w1}{w2,w3}{w4,w5}
  float m[NH], inv[NH];      // slow-path state
  const bool fast = (deg <= 64);

  if (fast) {
    bool val = lane < deg;
    s = val ? g_colsrc[lo + lane] : 0;
    const float2* ap = (const float2*)(g_alS + (size_t)s * NH);
    float2 p0 = ap[0], p1 = ap[1], p2 = ap[2];
    float v[NH] = {p0.x + ad[0], p0.y + ad[1], p1.x + ad[2],
                   p1.y + ad[3], p2.x + ad[4], p2.y + ad[5]};
    float mm[NH], w[NH], ss[NH];
    #pragma unroll
    for (int h = 0; h < NH; ++h) {
      v[h] = (v[h] > 0.f) ? v[h] : NEG * v[h];
      mm[h] = val ? v[h] : -1e30f;
    }
    #pragma unroll
    for (int h = 0; h < NH; ++h)
      #pragma unroll
      for (int off = 32; off > 0; off >>= 1)
        mm[h] = fmaxf(mm[h], __shfl_xor(mm[h], off));
    #pragma unroll
    for (int h = 0; h < NH; ++h) {
      w[h] = val ? __expf(v[h] - mm[h]) : 0.f;
      ss[h] = w[h];
    }
    #pragma unroll
    for (int h = 0; h < NH; ++h)
      #pragma unroll
      for (int off = 32; off > 0; off >>= 1)
        ss[h] += __shfl_xor(ss[h], off);
    #pragma unroll
    for (int h = 0; h < NH; ++h) w[h] *= __frcp_rn(ss[h] + 1e-16f);
    __half2 hp0 = __floats2half2_rn(w[0], w[1]);
    __half2 hp1 = __floats2half2_rn(w[2], w[3]);
    __half2 hp2 = __floats2half2_rn(w[4], w[5]);
    wpu[0] = *(unsigned*)&hp0; wpu[1] = *(unsigned*)&hp1; wpu[2] = *(unsigned*)&hp2;
  } else {
    // generic slow path (wave-uniform branch; statistically never taken)
    #pragma unroll
    for (int h = 0; h < NH; ++h) m[h] = -1e30f;
    for (int e = lo + lane; e < hi; e += 64) {
      int se = g_colsrc[e];
      #pragma unroll
      for (int h = 0; h < NH; ++h) {
        float v = g_alS[se * NH + h] + ad[h];
        v = (v > 0.f) ? v : NEG * v;
        m[h] = fmaxf(m[h], v);
      }
    }
    #pragma unroll
    for (int h = 0; h < NH; ++h)
      #pragma unroll
      for (int off = 32; off > 0; off >>= 1)
        m[h] = fmaxf(m[h], __shfl_xor(m[h], off));
    float ss[NH] = {0.f, 0.f, 0.f, 0.f, 0.f, 0.f};
    for (int e = lo + lane; e < hi; e += 64) {
      int se = g_colsrc[e];
      #pragma unroll
      for (int h = 0; h < NH; ++h) {
        float v = g_alS[se * NH + h] + ad[h];
        v = (v > 0.f) ? v : NEG * v;
        ss[h] += __expf(v - m[h]);
      }
    }
    #pragma unroll
    for (int h = 0; h < NH; ++h) {
      #pragma unroll
      for (int off = 32; off > 0; off >>= 1)
        ss[h] += __shfl_xor(ss[h], off);
      inv[h] = __frcp_rn(ss[h] + 1e-16f);
    }
  }

  // pass 2: weighted aggregation. lane owns dims {c*128+2*lane, +1}, c=0..2.
  float2 accA[3] = {{0.f, 0.f}, {0.f, 0.f}, {0.f, 0.f}};
  float2 accB[3] = {{0.f, 0.f}, {0.f, 0.f}, {0.f, 0.f}};

  auto body = [&](int ei, float2* acc) {
    int se;
    float wa[3];
    if (fast) {
      se = __shfl(s, ei);
      #pragma unroll
      for (int c = 0; c < 3; ++c) {
        unsigned u = __shfl((int)wpu[c], ei);
        __half2 hp = *(__half2*)&u;
        wa[c] = hiHalf ? __high2float(hp) : __low2float(hp);
      }
    } else {
      se = g_colsrc[lo + ei];
      const float* as = g_alS + (size_t)se * NH;
      float we[NH];
      #pragma unroll
      for (int h = 0; h < NH; ++h) {
        float v = as[h] + ad[h];
        v = (v > 0.f) ? v : NEG * v;
        we[h] = __expf(v - m[h]) * inv[h];
      }
      wa[0] = hiHalf ? we[1] : we[0];
      wa[1] = hiHalf ? we[3] : we[2];
      wa[2] = hiHalf ? we[5] : we[4];
    }
    const __half2* row = (const __half2*)(g_h16 + (size_t)se * FF);
    #pragma unroll
    for (int c = 0; c < 3; ++c) {
      float2 hv = __half22float2(row[c * 64 + lane]);
      acc[c].x = fmaf(wa[c], hv.x, acc[c].x);
      acc[c].y = fmaf(wa[c], hv.y, acc[c].y);
    }
  };

  int e = 0;
  for (; e + 1 < deg; e += 2) {
    body(e, accA);
    body(e + 1, accB);
  }
  if (e < deg) body(e, accA);

  #pragma unroll
  for (int c = 0; c < 3; ++c) {
    float2 bv = *(const float2*)(bias + c * 128 + lane * 2);
    float ox = fmaxf(accA[c].x + accB[c].x + bv.x, 0.f);
    float oy = fmaxf(accA[c].y + accB[c].y + bv.y, 0.f);
    size_t off = (size_t)node * FF + c * 128 + lane * 2;
    if (mode == 2) {
      unsigned short hx = f2bf(ox), hy = f2bf(oy);
      ushort2 hh = {hx, hy};
      ushort2 ll = {f2bf(ox - bf2f(hx)), f2bf(oy - bf2f(hy))};
      *(ushort2*)(g_featHi + off) = hh;
      *(ushort2*)(g_featLo + off) = ll;
    } else {
      float* out = mode ? g_bufC : g_bufB;
      float2 o = {ox, oy};
      *(float2*)(out + off) = o;
    }
  }
}

// ---------------- pooling: segmented accumulation over sorted batch ----------
__global__ __launch_bounds__(384) void k_pool_acc(const int* __restrict__ batch) {
  int n0 = blockIdx.x * PCH;
  if (n0 >= NN) return;
  int n1 = n0 + PCH; if (n1 > NN) n1 = NN;
  int d = threadIdx.x;
  int cur = batch[n0];
  float acc = 0.f;
  int cnt = 0;
  for (int n = n0; n < n1; ++n) {
    int g = batch[n];
    if (g != cur) {
      atomicAdd(&g_pool[cur * FF + d], acc);
      if (d == 0) atomicAdd(&g_gcnt[cur], cnt);
      acc = 0.f; cnt = 0; cur = g;
    }
    acc += g_bufB[(size_t)n * FF + d] + g_bufC[(size_t)n * FF + d];
    ++cnt;
  }
  atomicAdd(&g_pool[cur * FF + d], acc);
  if (d == 0) atomicAdd(&g_gcnt[cur], cnt);
}

// ---------------- finish: mean + readout MLP (fused) -------------------------
__global__ __launch_bounds__(384) void k_finish(const float* __restrict__ r1w,
                                                const float* __restrict__ r1b,
                                                const float* __restrict__ r2w,
                                                const float* __restrict__ r2b,
                                                float* __restrict__ dout) {
  int g = blockIdx.x;
  int d = threadIdx.x;
  __shared__ float xr[FF];
  __shared__ float hid[64];
  int cnt = g_gcnt[g];
  float denom = (cnt > 0) ? (float)cnt : 1.f;
  float v = g_pool[g * FF + d] / denom;
  xr[d] = v;
  dout[NG * NOUT + g * FF + d] = v;
  __syncthreads();
  if (d < 64) {
    float acc = r1b[d];
    for (int k = 0; k < FF; ++k) acc = fmaf(xr[k], r1w[k * 64 + d], acc);
    hid[d] = fmaxf(acc, 0.f);
  }
  __syncthreads();
  if (d < NOUT) {
    float o = r2b[d];
    #pragma unroll
    for (int j = 0; j < 64; ++j) o = fmaf(hid[j], r2w[j * NOUT + d], o);
    dout[g * NOUT + d] = o;
  }
}

// ---------------- orchestration ----------------------------------------------
extern "C" void kernel_launch(void* const* d_in, const int* in_sizes, int n_in,
                              void* d_out, int out_size, void* d_ws, size_t ws_size,
                              hipStream_t stream) {
  const float* x    = (const float*)d_in[0];
  const int* ei     = (const int*)d_in[1];
  const int* batch  = (const int*)d_in[2];
  const float* W1   = (const float*)d_in[3];
  const float* a1s  = (const float*)d_in[4];
  const float* a1d  = (const float*)d_in[5];
  const float* b1   = (const float*)d_in[6];
  const float* W2   = (const float*)d_in[7];
  const float* a2s  = (const float*)d_in[8];
  const float* a2d  = (const float*)d_in[9];
  const float* b2   = (const float*)d_in[10];
  const float* Ws1  = (const float*)d_in[11];
  const float* as1s = (const float*)d_in[12];
  const float* as1d = (const float*)d_in[13];
  const float* bs1  = (const float*)d_in[14];
  const float* Ws2  = (const float*)d_in[15];
  const float* as2s = (const float*)d_in[16];
  const float* as2d = (const float*)d_in[17];
  const float* bs2  = (const float*)d_in[18];
  const float* r1w  = (const float*)d_in[19];
  const float* r1b  = (const float*)d_in[20];
  const float* r2w  = (const float*)d_in[21];
  const float* r2b  = (const float*)d_in[22];
  float* out = (float*)d_out;

  dim3 b256(256);
  // weight prep (widx: 0=Ws1, 1=Ws2, 2=W1, 3=W2)
  k_wprep<<<dim3((FIN * FF + 255) / 256), b256, 0, stream>>>(Ws1, FIN, 0);
  k_wprep<<<dim3((FF * FF + 255) / 256), b256, 0, stream>>>(Ws2, FF, 1);
  k_wprep<<<dim3((FIN * FF + 255) / 256), b256, 0, stream>>>(W1, FIN, 2);
  k_wprep<<<dim3((FF * FF + 255) / 256), b256, 0, stream>>>(W2, FF, 3);
  // zero (CSR histogram + pool accumulators)
  k_zero<<<dim3((NG * FF + 255) / 256), b256, 0, stream>>>();
  k_hist<<<dim3((ETOT + 255) / 256), b256, 0, stream>>>(ei);
  // hierarchical scan
  k_scan_blk<<<dim3(NB), b256, 0, stream>>>();
  k_scan_top<<<dim3(1), dim3(128), 0, stream>>>();
  k_scan_add<<<dim3(NB), b256, 0, stream>>>();
  k_scatter<<<dim3((ETOT + 255) / 256), b256, 0, stream>>>(ei);
  // split x once (reused by both branch-1 convs)
  k_split<<<dim3(2048), b256, 0, stream>>>(x);

  dim3 gemmGrid((NN + 127) / 128, FF / 128);
  dim3 nodeGrid((NN + 3) / 4);

  // skip branch, layer 1: feat = split(relu(conv(x, Ws1)))
  k_gemm<<<gemmGrid, b256, 0, stream>>>(0, 0, FIN);
  k_alpha<<<nodeGrid, b256, 0, stream>>>(as1s, as1d);
  k_edge<<<nodeGrid, b256, 0, stream>>>(bs1, 2);
  // skip branch, layer 2: bufC = relu(conv(feat, Ws2))
  k_gemm<<<gemmGrid, b256, 0, stream>>>(1, 1, FF);
  k_alpha<<<nodeGrid, b256, 0, stream>>>(as2s, as2d);
  k_edge<<<nodeGrid, b256, 0, stream>>>(bs2, 1);
  // main branch, layer 1: feat = split(relu(conv(x, W1)))
  k_gemm<<<gemmGrid, b256, 0, stream>>>(0, 2, FIN);
  k_alpha<<<nodeGrid, b256, 0, stream>>>(a1s, a1d);
  k_edge<<<nodeGrid, b256, 0, stream>>>(b1, 2);
  // main branch, layer 2: bufB = relu(conv(feat, W2))
  k_gemm<<<gemmGrid, b256, 0, stream>>>(1, 3, FF);
  k_alpha<<<nodeGrid, b256, 0, stream>>>(a2s, a2d);
  k_edge<<<nodeGrid, b256, 0, stream>>>(b2, 0);
  // pool (bufB + bufC) and readout
  k_pool_acc<<<dim3((NN + PCH - 1) / PCH), dim3(384), 0, stream>>>(batch);
  k_finish<<<dim3(NG), dim3(384), 0, stream>>>(r1w, r1b, r2w, r2b, out);
}

// Round 8
// 383.645 us; speedup vs baseline: 2.0778x; 1.1702x over previous
//
#include <hip/hip_runtime.h>
#include <hip/hip_fp16.h>

#define NN 20000
#define EE 320000
#define ETOT 340000
#define FIN 128
#define NH 6
#define FF 384
#define NOUT 10
#define NG 64
#define NEG 0.2f
#define PCH 32
#define NB ((NN + 255) / 256)

typedef short short8 __attribute__((ext_vector_type(8)));
typedef float f32x4 __attribute__((ext_vector_type(4)));

// ---------------- static device storage (avoids ws_size dependence) ----------
__device__ __half g_h16[(size_t)NN * FF];   // gemm output h (fp16 gather table)
__device__ float g_bufB[(size_t)NN * FF];   // conv output / layer input
__device__ float g_bufC[(size_t)NN * FF];   // xs2 storage
__device__ unsigned short g_featHi[(size_t)NN * FF];
__device__ unsigned short g_featLo[(size_t)NN * FF];
__device__ unsigned short g_xHi[(size_t)NN * FIN];
__device__ unsigned short g_xLo[(size_t)NN * FIN];
__device__ unsigned short g_WtHi[4][FF * FF];  // transposed weights [col][k]
__device__ float g_alS[4][NN * NH];            // per-layer alpha_src (atomic acc)
__device__ float g_alD[4][NN * NH];
__device__ int g_rowptr[NN + 1];
__device__ int g_cnt[NN];
__device__ int g_cur[NN];
__device__ int g_blocksum[NB];
__device__ int g_colsrc[ETOT];
__device__ float g_pool[NG * FF];
__device__ int g_gcnt[NG];

// ---------------- helpers ----------------------------------------------------
__device__ __forceinline__ unsigned short f2bf(float f) {
  unsigned u = __float_as_uint(f);
  u += 0x7FFFu + ((u >> 16) & 1u);
  return (unsigned short)(u >> 16);
}
__device__ __forceinline__ float bf2f(unsigned short s) {
  return __uint_as_float(((unsigned)s) << 16);
}

__device__ __forceinline__ void gl_lds16(const void* g, void* l) {
  __builtin_amdgcn_global_load_lds(
      (const __attribute__((address_space(1))) unsigned int*)(unsigned long long)g,
      (__attribute__((address_space(3))) unsigned int*)(unsigned int)(unsigned long long)l,
      16, 0, 0);
}

__device__ __forceinline__ void mfma_acc(f32x4& c, short8 a, short8 b) {
  asm("v_mfma_f32_16x16x32_bf16 %0, %1, %2, %0" : "+v"(c) : "v"(a), "v"(b));
}

// fp16-source FMA into f32 acc: acc.x += f16lo(hv)*w ; acc.y += f16hi(hv)*w
__device__ __forceinline__ void fmix(float2& acc, unsigned hv, float w) {
  asm("v_fma_mix_f32 %0, %2, %3, %0 op_sel:[0,0,0] op_sel_hi:[1,0,0]\n\t"
      "v_fma_mix_f32 %1, %2, %3, %1 op_sel:[1,0,0] op_sel_hi:[1,0,0]"
      : "+v"(acc.x), "+v"(acc.y)
      : "v"(hv), "v"(w));
}

// ---------------- weight prep: fp32 [K,F] -> bf16 hi transposed [F][K] -------
__global__ __launch_bounds__(256) void k_wprep(const float* __restrict__ W, int K, int widx) {
  int i = blockIdx.x * 256 + threadIdx.x;
  if (i >= K * FF) return;
  int k = i / FF, c = i % FF;
  g_WtHi[widx][c * K + k] = f2bf(W[i]);
}

// ---------------- zero pass (CSR histogram + pool + alpha accumulators) ------
__global__ __launch_bounds__(256) void k_zero() {
  int i = blockIdx.x * 256 + threadIdx.x;
  if (i < NN) g_cnt[i] = 0;
  if (i < NG * FF) g_pool[i] = 0.f;
  if (i < NG) g_gcnt[i] = 0;
  if (i < 4 * NN * NH) {
    (&g_alS[0][0])[i] = 0.f;
    (&g_alD[0][0])[i] = 0.f;
  }
}

__global__ __launch_bounds__(256) void k_hist(const int* __restrict__ ei) {
  int i = blockIdx.x * 256 + threadIdx.x;
  if (i >= ETOT) return;
  int d = (i < EE) ? ei[EE + i] : (i - EE);
  atomicAdd(&g_cnt[d], 1);
}

// ---------------- hierarchical scan (3 launches, shuffle-based) --------------
__global__ __launch_bounds__(256) void k_scan_blk() {
  int b = blockIdx.x;
  int tid = threadIdx.x;
  int i = b * 256 + tid;
  int lane = tid & 63, wid = tid >> 6;
  int v = (i < NN) ? g_cnt[i] : 0;
  int s = v;
  #pragma unroll
  for (int off = 1; off < 64; off <<= 1) {
    int t = __shfl_up(s, off);
    if (lane >= off) s += t;
  }
  __shared__ int wsum[4];
  if (lane == 63) wsum[wid] = s;
  __syncthreads();
  int woff = 0;
  #pragma unroll
  for (int w = 0; w < 4; ++w) woff += (w < wid) ? wsum[w] : 0;
  if (i < NN) g_rowptr[i] = woff + s - v;   // block-local exclusive
  if (tid == 0) g_blocksum[b] = wsum[0] + wsum[1] + wsum[2] + wsum[3];
}

__global__ __launch_bounds__(128) void k_scan_top() {
  int tid = threadIdx.x;
  int lane = tid & 63, wid = tid >> 6;
  int v = (tid < NB) ? g_blocksum[tid] : 0;
  int s = v;
  #pragma unroll
  for (int off = 1; off < 64; off <<= 1) {
    int t = __shfl_up(s, off);
    if (lane >= off) s += t;
  }
  __shared__ int wsum[2];
  if (lane == 63) wsum[wid] = s;
  __syncthreads();
  int woff = (wid == 1) ? wsum[0] : 0;
  int excl = woff + s - v;
  if (tid < NB) g_blocksum[tid] = excl;
  if (tid == NB - 1) g_rowptr[NN] = excl + v;
}

__global__ __launch_bounds__(256) void k_scan_add() {
  int i = blockIdx.x * 256 + threadIdx.x;
  if (i >= NN) return;
  int r = g_rowptr[i] + g_blocksum[blockIdx.x];
  g_rowptr[i] = r;
  g_cur[i] = r;
}

__global__ __launch_bounds__(256) void k_scatter(const int* __restrict__ ei) {
  int i = blockIdx.x * 256 + threadIdx.x;
  if (i >= ETOT) return;
  int s, d;
  if (i < EE) { s = ei[i]; d = ei[EE + i]; } else { s = d = i - EE; }
  int pos = atomicAdd(&g_cur[d], 1);
  g_colsrc[pos] = s;
}

// ---------------- fp32 -> bf16 hi/lo split (x input only) --------------------
__global__ __launch_bounds__(256) void k_split(const float* __restrict__ xin) {
  int n4 = (NN * FIN) >> 2;
  const float4* s4 = (const float4*)xin;
  ushort4* oh4 = (ushort4*)g_xHi;
  ushort4* ol4 = (ushort4*)g_xLo;
  for (int i = blockIdx.x * blockDim.x + threadIdx.x; i < n4; i += gridDim.x * blockDim.x) {
    float4 v = s4[i];
    ushort4 h, l;
    h.x = f2bf(v.x); l.x = f2bf(v.x - bf2f(h.x));
    h.y = f2bf(v.y); l.y = f2bf(v.y - bf2f(h.y));
    h.z = f2bf(v.z); l.z = f2bf(v.z - bf2f(h.z));
    h.w = f2bf(v.w); l.w = f2bf(v.w - bf2f(h.w));
    oh4[i] = h; ol4[i] = l;
  }
}

// ---------------- GEMM: h16 = A @ WtHi^T (2-term A-split, fp32 acc) ----------
// epilogue: fused alpha partials (each wave's 64-col stripe = one head).
__global__ __launch_bounds__(256) void k_gemm(int asel, int widx, int K, int layer,
                                              const float* __restrict__ asr,
                                              const float* __restrict__ adt) {
  __shared__ unsigned short lA[128 * 64];
  __shared__ unsigned short lB[128 * 64];
  const unsigned short* Ah = asel ? g_featHi : g_xHi;
  const unsigned short* Al = asel ? g_featLo : g_xLo;
  const unsigned short* Bh = g_WtHi[widx];
  const int m0 = blockIdx.x * 128;
  const int n0 = blockIdx.y * 128;
  const int tid = threadIdx.x;
  const int wave = tid >> 6, lane = tid & 63;
  const int wm = wave >> 1, wn = wave & 1;
  const int srow = lane >> 3;        // row within 8-row chunk
  const int scol = (lane & 7) * 8;   // k-element offset

  f32x4 acc[4][4] = {};

  for (int t = 0; t < 2; ++t) {
    const unsigned short* Ap = t ? Al : Ah;
    for (int k0 = 0; k0 < K; k0 += 64) {
      __syncthreads();  // prior reads done before overwrite
      #pragma unroll
      for (int it = 0; it < 4; ++it) {
        int c = wave * 4 + it;
        int rA = c * 8 + srow;
        int gr = m0 + rA; gr = (gr < NN) ? gr : (NN - 1);
        gl_lds16(Ap + (size_t)gr * K + k0 + scol, (unsigned short*)lA + c * 512);
        int cB = n0 + rA;  // always < 384
        gl_lds16(Bh + (size_t)cB * K + k0 + scol, (unsigned short*)lB + c * 512);
      }
      __syncthreads();  // drains vmcnt for global_load_lds
      #pragma unroll
      for (int kk = 0; kk < 64; kk += 32) {
        const int kb = kk + (lane >> 4) * 8;
        const int r16 = lane & 15;
        short8 af[4], bfr[4];
        #pragma unroll
        for (int mf = 0; mf < 4; ++mf)
          af[mf] = *(const short8*)&lA[(wm * 64 + mf * 16 + r16) * 64 + kb];
        #pragma unroll
        for (int nf = 0; nf < 4; ++nf)
          bfr[nf] = *(const short8*)&lB[(wn * 64 + nf * 16 + r16) * 64 + kb];
        #pragma unroll
        for (int mf = 0; mf < 4; ++mf)
          #pragma unroll
          for (int nf = 0; nf < 4; ++nf)
            mfma_acc(acc[mf][nf], af[mf], bfr[nf]);
      }
    }
  }
  asm volatile("s_nop 7\n\ts_nop 7" :::);

  const int r16 = lane & 15;
  // ---- C-write (fp16 table) ----
  #pragma unroll
  for (int mf = 0; mf < 4; ++mf) {
    #pragma unroll
    for (int nf = 0; nf < 4; ++nf) {
      int col = n0 + wn * 64 + nf * 16 + r16;
      int rb = m0 + wm * 64 + mf * 16 + ((lane >> 4) << 2);
      #pragma unroll
      for (int j = 0; j < 4; ++j) {
        int r = rb + j;
        if (r < NN) g_h16[(size_t)r * FF + col] = __float2half(acc[mf][nf][j]);
      }
    }
  }
  // ---- fused alpha partials: head = by*2 + wn ----
  const int hd = blockIdx.y * 2 + wn;
  float as_v[4], ad_v[4];
  #pragma unroll
  for (int nf = 0; nf < 4; ++nf) {
    as_v[nf] = asr[hd * 64 + nf * 16 + r16];
    ad_v[nf] = adt[hd * 64 + nf * 16 + r16];
  }
  float* alS = g_alS[layer];
  float* alD = g_alD[layer];
  #pragma unroll
  for (int mf = 0; mf < 4; ++mf) {
    #pragma unroll
    for (int j = 0; j < 4; ++j) {
      float ps = 0.f, pd = 0.f;
      #pragma unroll
      for (int nf = 0; nf < 4; ++nf) {
        ps = fmaf(acc[mf][nf][j], as_v[nf], ps);
        pd = fmaf(acc[mf][nf][j], ad_v[nf], pd);
      }
      #pragma unroll
      for (int off = 1; off < 16; off <<= 1) {
        ps += __shfl_xor(ps, off);
        pd += __shfl_xor(pd, off);
      }
      int r = m0 + wm * 64 + mf * 16 + ((lane >> 4) << 2) + j;
      if (r16 == 0 && r < NN) {
        atomicAdd(&alS[r * NH + hd], ps);
        atomicAdd(&alD[r * NH + hd], pd);
      }
    }
  }
}

// ---------------- softmax + aggregation, one wave per destination node -------
// fast path (deg<=64): lane-parallel softmax; normalized fp16 weights broadcast
// via shfl; pass-2 unrolled x4 with v_fma_mix (fp16 operand, f32 acc).
// mode: 0 -> float out to bufB; 1 -> float out to bufC; 2 -> bf16 hi/lo feat.
__global__ __launch_bounds__(256) void k_edge(const float* __restrict__ bias, int mode, int layer) {
  int node = blockIdx.x * 4 + (threadIdx.x >> 6);
  int lane = threadIdx.x & 63;
  if (node >= NN) return;
  const float* aS = g_alS[layer];
  const float* aD = g_alD[layer];
  const int lo = g_rowptr[node], hi = g_rowptr[node + 1];
  const int deg = hi - lo;
  float ad[NH];
  #pragma unroll
  for (int h = 0; h < NH; ++h) ad[h] = aD[node * NH + h];

  const bool hiHalf = (lane >= 32);
  int s = 0;                 // this lane's source (fast path)
  unsigned wpu[3];           // packed normalized weights {w0,w1}{w2,w3}{w4,w5}
  float m[NH], inv[NH];      // slow-path state
  const bool fast = (deg <= 64);

  auto wsel = [&](int u) -> float {
    __half2 hp = *(__half2*)&u;
    return hiHalf ? __high2float(hp) : __low2float(hp);
  };

  if (fast) {
    bool val = lane < deg;
    s = val ? g_colsrc[lo + lane] : 0;
    const float2* ap = (const float2*)(aS + (size_t)s * NH);
    float2 p0 = ap[0], p1 = ap[1], p2 = ap[2];
    float v[NH] = {p0.x + ad[0], p0.y + ad[1], p1.x + ad[2],
                   p1.y + ad[3], p2.x + ad[4], p2.y + ad[5]};
    float mm[NH], w[NH], ss[NH];
    #pragma unroll
    for (int h = 0; h < NH; ++h) {
      v[h] = (v[h] > 0.f) ? v[h] : NEG * v[h];
      mm[h] = val ? v[h] : -1e30f;
    }
    #pragma unroll
    for (int h = 0; h < NH; ++h)
      #pragma unroll
      for (int off = 32; off > 0; off >>= 1)
        mm[h] = fmaxf(mm[h], __shfl_xor(mm[h], off));
    #pragma unroll
    for (int h = 0; h < NH; ++h) {
      w[h] = val ? __expf(v[h] - mm[h]) : 0.f;
      ss[h] = w[h];
    }
    #pragma unroll
    for (int h = 0; h < NH; ++h)
      #pragma unroll
      for (int off = 32; off > 0; off >>= 1)
        ss[h] += __shfl_xor(ss[h], off);
    #pragma unroll
    for (int h = 0; h < NH; ++h) w[h] *= __frcp_rn(ss[h] + 1e-16f);
    __half2 hp0 = __floats2half2_rn(w[0], w[1]);
    __half2 hp1 = __floats2half2_rn(w[2], w[3]);
    __half2 hp2 = __floats2half2_rn(w[4], w[5]);
    wpu[0] = *(unsigned*)&hp0; wpu[1] = *(unsigned*)&hp1; wpu[2] = *(unsigned*)&hp2;
  } else {
    // generic slow path (wave-uniform branch; statistically never taken)
    #pragma unroll
    for (int h = 0; h < NH; ++h) m[h] = -1e30f;
    for (int e = lo + lane; e < hi; e += 64) {
      int se = g_colsrc[e];
      #pragma unroll
      for (int h = 0; h < NH; ++h) {
        float v = aS[se * NH + h] + ad[h];
        v = (v > 0.f) ? v : NEG * v;
        m[h] = fmaxf(m[h], v);
      }
    }
    #pragma unroll
    for (int h = 0; h < NH; ++h)
      #pragma unroll
      for (int off = 32; off > 0; off >>= 1)
        m[h] = fmaxf(m[h], __shfl_xor(m[h], off));
    float ss[NH] = {0.f, 0.f, 0.f, 0.f, 0.f, 0.f};
    for (int e = lo + lane; e < hi; e += 64) {
      int se = g_colsrc[e];
      #pragma unroll
      for (int h = 0; h < NH; ++h) {
        float v = aS[se * NH + h] + ad[h];
        v = (v > 0.f) ? v : NEG * v;
        ss[h] += __expf(v - m[h]);
      }
    }
    #pragma unroll
    for (int h = 0; h < NH; ++h) {
      #pragma unroll
      for (int off = 32; off > 0; off >>= 1)
        ss[h] += __shfl_xor(ss[h], off);
      inv[h] = __frcp_rn(ss[h] + 1e-16f);
    }
  }

  // pass 2: weighted aggregation. lane owns dims {c*128+2*lane, +1}, c=0..2.
  float2 accA[3] = {{0.f,0.f},{0.f,0.f},{0.f,0.f}};
  float2 accB[3] = {{0.f,0.f},{0.f,0.f},{0.f,0.f}};
  float2 accC[3] = {{0.f,0.f},{0.f,0.f},{0.f,0.f}};
  float2 accD[3] = {{0.f,0.f},{0.f,0.f},{0.f,0.f}};

  if (fast) {
    int e = 0;
    for (; e + 3 < deg; e += 4) {
      int se0 = __shfl(s, e + 0), se1 = __shfl(s, e + 1);
      int se2 = __shfl(s, e + 2), se3 = __shfl(s, e + 3);
      const unsigned* r0 = (const unsigned*)(g_h16 + (size_t)se0 * FF) + lane;
      const unsigned* r1 = (const unsigned*)(g_h16 + (size_t)se1 * FF) + lane;
      const unsigned* r2 = (const unsigned*)(g_h16 + (size_t)se2 * FF) + lane;
      const unsigned* r3 = (const unsigned*)(g_h16 + (size_t)se3 * FF) + lane;
      unsigned h0[3] = {r0[0], r0[64], r0[128]};
      unsigned h1[3] = {r1[0], r1[64], r1[128]};
      unsigned h2[3] = {r2[0], r2[64], r2[128]};
      unsigned h3[3] = {r3[0], r3[64], r3[128]};
      #pragma unroll
      for (int c = 0; c < 3; ++c) {
        fmix(accA[c], h0[c], wsel(__shfl((int)wpu[c], e + 0)));
        fmix(accB[c], h1[c], wsel(__shfl((int)wpu[c], e + 1)));
        fmix(accC[c], h2[c], wsel(__shfl((int)wpu[c], e + 2)));
        fmix(accD[c], h3[c], wsel(__shfl((int)wpu[c], e + 3)));
      }
    }
    for (; e < deg; ++e) {
      int se = __shfl(s, e);
      const unsigned* r0 = (const unsigned*)(g_h16 + (size_t)se * FF) + lane;
      unsigned h0[3] = {r0[0], r0[64], r0[128]};
      #pragma unroll
      for (int c = 0; c < 3; ++c)
        fmix(accA[c], h0[c], wsel(__shfl((int)wpu[c], e)));
    }
  } else {
    for (int e = 0; e < deg; ++e) {
      int se = g_colsrc[lo + e];
      const float* as = aS + (size_t)se * NH;
      float we[NH];
      #pragma unroll
      for (int h = 0; h < NH; ++h) {
        float v = as[h] + ad[h];
        v = (v > 0.f) ? v : NEG * v;
        we[h] = __expf(v - m[h]) * inv[h];
      }
      float wa[3] = {hiHalf ? we[1] : we[0], hiHalf ? we[3] : we[2],
                     hiHalf ? we[5] : we[4]};
      const unsigned* r0 = (const unsigned*)(g_h16 + (size_t)se * FF) + lane;
      unsigned h0[3] = {r0[0], r0[64], r0[128]};
      #pragma unroll
      for (int c = 0; c < 3; ++c) fmix(accA[c], h0[c], wa[c]);
    }
  }

  #pragma unroll
  for (int c = 0; c < 3; ++c) {
    float2 bv = *(const float2*)(bias + c * 128 + lane * 2);
    float ox = fmaxf(accA[c].x + accB[c].x + accC[c].x + accD[c].x + bv.x, 0.f);
    float oy = fmaxf(accA[c].y + accB[c].y + accC[c].y + accD[c].y + bv.y, 0.f);
    size_t off = (size_t)node * FF + c * 128 + lane * 2;
    if (mode == 2) {
      unsigned short hx = f2bf(ox), hy = f2bf(oy);
      ushort2 hh = {hx, hy};
      ushort2 ll = {f2bf(ox - bf2f(hx)), f2bf(oy - bf2f(hy))};
      *(ushort2*)(g_featHi + off) = hh;
      *(ushort2*)(g_featLo + off) = ll;
    } else {
      float* out = mode ? g_bufC : g_bufB;
      float2 o = {ox, oy};
      *(float2*)(out + off) = o;
    }
  }
}

// ---------------- pooling: segmented accumulation over sorted batch ----------
__global__ __launch_bounds__(384) void k_pool_acc(const int* __restrict__ batch) {
  int n0 = blockIdx.x * PCH;
  if (n0 >= NN) return;
  int n1 = n0 + PCH; if (n1 > NN) n1 = NN;
  int d = threadIdx.x;
  int cur = batch[n0];
  float acc = 0.f;
  int cnt = 0;
  for (int n = n0; n < n1; ++n) {
    int g = batch[n];
    if (g != cur) {
      atomicAdd(&g_pool[cur * FF + d], acc);
      if (d == 0) atomicAdd(&g_gcnt[cur], cnt);
      acc = 0.f; cnt = 0; cur = g;
    }
    acc += g_bufB[(size_t)n * FF + d] + g_bufC[(size_t)n * FF + d];
    ++cnt;
  }
  atomicAdd(&g_pool[cur * FF + d], acc);
  if (d == 0) atomicAdd(&g_gcnt[cur], cnt);
}

// ---------------- finish: mean + readout MLP (fused) -------------------------
__global__ __launch_bounds__(384) void k_finish(const float* __restrict__ r1w,
                                                const float* __restrict__ r1b,
                                                const float* __restrict__ r2w,
                                                const float* __restrict__ r2b,
                                                float* __restrict__ dout) {
  int g = blockIdx.x;
  int d = threadIdx.x;
  __shared__ float xr[FF];
  __shared__ float hid[64];
  int cnt = g_gcnt[g];
  float denom = (cnt > 0) ? (float)cnt : 1.f;
  float v = g_pool[g * FF + d] / denom;
  xr[d] = v;
  dout[NG * NOUT + g * FF + d] = v;
  __syncthreads();
  if (d < 64) {
    float acc = r1b[d];
    for (int k = 0; k < FF; ++k) acc = fmaf(xr[k], r1w[k * 64 + d], acc);
    hid[d] = fmaxf(acc, 0.f);
  }
  __syncthreads();
  if (d < NOUT) {
    float o = r2b[d];
    #pragma unroll
    for (int j = 0; j < 64; ++j) o = fmaf(hid[j], r2w[j * NOUT + d], o);
    dout[g * NOUT + d] = o;
  }
}

// ---------------- orchestration ----------------------------------------------
extern "C" void kernel_launch(void* const* d_in, const int* in_sizes, int n_in,
                              void* d_out, int out_size, void* d_ws, size_t ws_size,
                              hipStream_t stream) {
  const float* x    = (const float*)d_in[0];
  const int* ei     = (const int*)d_in[1];
  const int* batch  = (const int*)d_in[2];
  const float* W1   = (const float*)d_in[3];
  const float* a1s  = (const float*)d_in[4];
  const float* a1d  = (const float*)d_in[5];
  const float* b1   = (const float*)d_in[6];
  const float* W2   = (const float*)d_in[7];
  const float* a2s  = (const float*)d_in[8];
  const float* a2d  = (const float*)d_in[9];
  const float* b2   = (const float*)d_in[10];
  const float* Ws1  = (const float*)d_in[11];
  const float* as1s = (const float*)d_in[12];
  const float* as1d = (const float*)d_in[13];
  const float* bs1  = (const float*)d_in[14];
  const float* Ws2  = (const float*)d_in[15];
  const float* as2s = (const float*)d_in[16];
  const float* as2d = (const float*)d_in[17];
  const float* bs2  = (const float*)d_in[18];
  const float* r1w  = (const float*)d_in[19];
  const float* r1b  = (const float*)d_in[20];
  const float* r2w  = (const float*)d_in[21];
  const float* r2b  = (const float*)d_in[22];
  float* out = (float*)d_out;

  dim3 b256(256);
  // weight prep (widx: 0=Ws1, 1=Ws2, 2=W1, 3=W2)
  k_wprep<<<dim3((FIN * FF + 255) / 256), b256, 0, stream>>>(Ws1, FIN, 0);
  k_wprep<<<dim3((FF * FF + 255) / 256), b256, 0, stream>>>(Ws2, FF, 1);
  k_wprep<<<dim3((FIN * FF + 255) / 256), b256, 0, stream>>>(W1, FIN, 2);
  k_wprep<<<dim3((FF * FF + 255) / 256), b256, 0, stream>>>(W2, FF, 3);
  // zero (CSR histogram + pool + per-layer alpha accumulators)
  k_zero<<<dim3((4 * NN * NH + 255) / 256), b256, 0, stream>>>();
  k_hist<<<dim3((ETOT + 255) / 256), b256, 0, stream>>>(ei);
  // hierarchical scan
  k_scan_blk<<<dim3(NB), b256, 0, stream>>>();
  k_scan_top<<<dim3(1), dim3(128), 0, stream>>>();
  k_scan_add<<<dim3(NB), b256, 0, stream>>>();
  k_scatter<<<dim3((ETOT + 255) / 256), b256, 0, stream>>>(ei);
  // split x once (reused by both branch-1 convs)
  k_split<<<dim3(2048), b256, 0, stream>>>(x);

  dim3 gemmGrid((NN + 127) / 128, FF / 128);
  dim3 nodeGrid((NN + 3) / 4);

  // skip branch, layer 1 (layer=0): feat = split(relu(conv(x, Ws1)))
  k_gemm<<<gemmGrid, b256, 0, stream>>>(0, 0, FIN, 0, as1s, as1d);
  k_edge<<<nodeGrid, b256, 0, stream>>>(bs1, 2, 0);
  // skip branch, layer 2 (layer=1): bufC = relu(conv(feat, Ws2))
  k_gemm<<<gemmGrid, b256, 0, stream>>>(1, 1, FF, 1, as2s, as2d);
  k_edge<<<nodeGrid, b256, 0, stream>>>(bs2, 1, 1);
  // main branch, layer 1 (layer=2): feat = split(relu(conv(x, W1)))
  k_gemm<<<gemmGrid, b256, 0, stream>>>(0, 2, FIN, 2, a1s, a1d);
  k_edge<<<nodeGrid, b256, 0, stream>>>(b1, 2, 2);
  // main branch, layer 2 (layer=3): bufB = relu(conv(feat, W2))
  k_gemm<<<gemmGrid, b256, 0, stream>>>(1, 3, FF, 3, a2s, a2d);
  k_edge<<<nodeGrid, b256, 0, stream>>>(b2, 0, 3);
  // pool (bufB + bufC) and readout
  k_pool_acc<<<dim3((NN + PCH - 1) / PCH), dim3(384), 0, stream>>>(batch);
  k_finish<<<dim3(NG), dim3(384), 0, stream>>>(r1w, r1b, r2w, r2b, out);
}